// Round 11
// baseline (895.745 us; speedup 1.0000x reference)
//
#include <hip/hip_runtime.h>

#define H 128
#define LPAD 132
#define BM 64

typedef __attribute__((ext_vector_type(8))) short bf8;
typedef __attribute__((ext_vector_type(4))) float f4;
typedef __attribute__((ext_vector_type(4))) short s4;

__device__ __forceinline__ short f2bf(float f) {
    unsigned u = __float_as_uint(f);
    unsigned r = u + 0x7FFFu + ((u >> 16) & 1u);   // round-to-nearest-even
    return (short)(r >> 16);
}
__device__ __forceinline__ float bf2f(unsigned lo16) {
    return __uint_as_float((lo16 & 0xFFFFu) << 16);
}

// ================= weight packing =================
// packed[m][kc][lane][i] = bf16( W[kc*32 + (lane>>4)*8 + i][m*16 + (lane&15)] ), 0 if k>=K
__global__ void pack_w(const float* __restrict__ W, short* __restrict__ out, int K, int KC) {
    const int layer = blockIdx.z;
    const float* Wl = W + (size_t)layer * K * H;
    short* ol = out + (size_t)layer * 8 * KC * 512;
    const int total = 8 * KC * 512;
    for (int idx = blockIdx.x * blockDim.x + threadIdx.x; idx < total; idx += gridDim.x * blockDim.x) {
        int i = idx & 7;
        int lane = (idx >> 3) & 63;
        int v = idx >> 9;
        int kc = v % KC;
        int m = v / KC;
        int k = kc * 32 + (lane >> 4) * 8 + i;
        int c = m * 16 + (lane & 15);
        float val = (k < K) ? Wl[(size_t)k * H + c] : 0.f;
        ol[idx] = f2bf(val);
    }
}

// TS weights: c'<128 -> edge_w1[l][k][c'] (tgt), c'>=128 -> edge_w1[l][128+k][c'-128] (src)
__global__ void pack_wts(const float* __restrict__ W /*[L][259][128]*/, short* __restrict__ out) {
    const int layer = blockIdx.z;
    const float* Wl = W + (size_t)layer * 259 * 128;
    short* ol = out + (size_t)layer * 16 * 4 * 512;
    const int total = 16 * 4 * 512;
    for (int idx = blockIdx.x * blockDim.x + threadIdx.x; idx < total; idx += gridDim.x * blockDim.x) {
        int i = idx & 7;
        int lane = (idx >> 3) & 63;
        int v = idx >> 9;
        int kc = v & 3;
        int m = v >> 2;
        int k = kc * 32 + (lane >> 4) * 8 + i;
        int c = m * 16 + (lane & 15);     // 0..255
        float val = (c < 128) ? Wl[(size_t)k * 128 + c] : Wl[(size_t)(128 + k) * 128 + (c - 128)];
        ol[idx] = f2bf(val);
    }
}

// ================= CSR build =================
__global__ void csr_count(const int* __restrict__ tgt, int* __restrict__ cnt, int E) {
    int e = blockIdx.x * blockDim.x + threadIdx.x;
    if (e < E) atomicAdd(&cnt[tgt[e]], 1);
}

#define SCAN_T 1024
__global__ __launch_bounds__(SCAN_T) void scan_excl(const int* __restrict__ cnt,
                                                    int* __restrict__ start, int n) {
    __shared__ int part[SCAN_T];
    int t = threadIdx.x;
    int chunk = (n + SCAN_T - 1) / SCAN_T;
    int lo = t * chunk, hi = min(lo + chunk, n);
    int s = 0;
    for (int i = lo; i < hi; ++i) s += cnt[i];
    part[t] = s;
    __syncthreads();
    for (int off = 1; off < SCAN_T; off <<= 1) {
        int v = (t >= off) ? part[t - off] : 0;
        __syncthreads();
        part[t] += v;
        __syncthreads();
    }
    int base = (t > 0) ? part[t - 1] : 0;
    for (int i = lo; i < hi; ++i) { start[i] = base; base += cnt[i]; }
}

// scatter + reorder fused: sorted position p gets edge e's (src,tgt) pair + attr ([E][4] bf16)
__global__ void csr_scatter_reorder(const int* __restrict__ tgtI, const int* __restrict__ srcI,
                                    const float* __restrict__ eattr,
                                    int* __restrict__ start,
                                    int2* __restrict__ stpair,
                                    short* __restrict__ attrb, int E) {
    int e = blockIdx.x * blockDim.x + threadIdx.x;
    if (e >= E) return;
    int t = tgtI[e];
    int p = atomicAdd(&start[t], 1);
    stpair[p] = make_int2(srcI[e], t);
    s4 vv = {};
    vv[0] = f2bf(eattr[(size_t)e * 3 + 0]);
    vv[1] = f2bf(eattr[(size_t)e * 3 + 1]);
    vv[2] = f2bf(eattr[(size_t)e * 3 + 2]);
    *(s4*)(attrb + (size_t)p * 4) = vv;
}

// ========== TS precompute (layer 0 only): Tarr/Sarr bf16 + fused aggr zeroing ==========
__global__ __launch_bounds__(512, 4) void ts_mfma(
    const short* __restrict__ hbf, const short* __restrict__ wtsp,
    const float* __restrict__ b1,
    short* __restrict__ Tarr, short* __restrict__ Sarr,
    float* __restrict__ aggr, int N) {
    __shared__ __align__(16) short sW[16 * 4 * 512];   // 64 KB
    const int tid = threadIdx.x;
    for (int t = tid; t < 16 * 4 * 512 / 8; t += 512) ((uint4*)sW)[t] = ((const uint4*)wtsp)[t];
    __syncthreads();

    const int lane = tid & 63;
    const int wv = tid >> 6;          // 0..7
    const int g = lane >> 4;
    const int er = lane & 15;
    const int n = blockIdx.x * 128 + wv * 16 + er;
    const int nC = (n < N) ? n : 0;
    const bf8* rT = (const bf8*)(hbf + (size_t)nC * H);

    f4 acc[16] = {};
#pragma unroll
    for (int kc = 0; kc < 4; ++kc) {
        bf8 b = rT[kc * 4 + g];
#pragma unroll
        for (int m = 0; m < 16; ++m)
            acc[m] = __builtin_amdgcn_mfma_f32_16x16x32_bf16(
                *(const bf8*)(sW + ((m * 4 + kc) * 64 + lane) * 8), b, acc[m], 0, 0, 0);
    }
    if (n >= N) return;
    short* oT = Tarr + (size_t)n * 128;
    short* oS = Sarr + (size_t)n * 128;
    float* oZ = aggr + (size_t)n * 128;
    const f4 zz = {0.f, 0.f, 0.f, 0.f};
#pragma unroll
    for (int m = 0; m < 16; ++m) {
        f4 v = acc[m];
        if (m < 8) {
            f4 bb = *(const f4*)(b1 + m * 16 + 4 * g);
            v = v + bb;
            *(f4*)(oZ + m * 16 + 4 * g) = zz;   // fused aggr zeroing
        }
        unsigned p0, p1;
        asm("v_cvt_pk_bf16_f32 %0, %1, %2" : "=v"(p0) : "v"(v[0]), "v"(v[1]));
        asm("v_cvt_pk_bf16_f32 %0, %1, %2" : "=v"(p1) : "v"(v[2]), "v"(v[3]));
        uint2 uu; uu.x = p0; uu.y = p1;
        if (m < 8) *(uint2*)(oT + m * 16 + 4 * g) = uu;
        else       *(uint2*)(oS + (m - 8) * 16 + 4 * g) = uu;
    }
}

// ================= fused edge kernel (128 edges / 512 threads, half-sized smsg) =================
// hid = relu(T[tgt]+S[src]+attr*W1a); msg = LN(hid@W2+b2); two-pass LDS segmented sum -> atomicAdd aggr
__global__ __launch_bounds__(512, 4) void edge_fused(
    const short* __restrict__ Tarr, const short* __restrict__ Sarr,
    const short* __restrict__ attrbf,
    const int2* __restrict__ stpair,
    const short* __restrict__ w2p,
    const float* __restrict__ w1aG,   // [3][128] f32 (attr rows of edge_w1)
    const float* __restrict__ b2,
    const float* __restrict__ gamma, const float* __restrict__ beta,
    float* __restrict__ aggr, int nrows) {
    __shared__ __align__(16) short sW2[8 * 4 * 512];     // 32 KB
    __shared__ float sw1a[3 * 128];                      // 1.5 KB
    __shared__ __align__(16) unsigned smsg[64 * 64];     // 16 KB (one half at a time)
    __shared__ int stgt[128];

    const int tid = threadIdx.x;
    for (int t = tid; t < 8 * 4 * 512 / 8; t += 512) ((uint4*)sW2)[t] = ((const uint4*)w2p)[t];
    if (tid < 384) sw1a[tid] = w1aG[tid];
    const int e0b = blockIdx.x * 128;
    if (tid < 128) {
        int ee = e0b + tid;
        stgt[tid] = (ee < nrows) ? stpair[ee].y : -1;
    }
    __syncthreads();

    const int lane = tid & 63;
    const int wv = tid >> 6;          // 0..7
    const int g = lane >> 4;
    const int er = lane & 15;
    const int le = wv * 16 + er;      // local edge 0..127
    const int e = e0b + le;
    const bool valid = e < nrows;
    const int eC = valid ? e : 0;
    const int2 st = stpair[eC];
    const int tS = st.x;
    const int tT = st.y;

    uint2 au = *(const uint2*)(attrbf + (size_t)eC * 4);
    const float at0 = bf2f(au.x), at1 = bf2f(au.x >> 16), at2 = bf2f(au.y);

    const short* Tp = Tarr + (size_t)tT * 128;
    const short* Sp = Sarr + (size_t)tS * 128;

    // ---------- hid build + GEMM2 ----------
    f4 acc2[8] = {};
#pragma unroll
    for (int kc2 = 0; kc2 < 4; ++kc2) {
        const int c0 = kc2 * 32 + 8 * g;
        uint4 tu = *(const uint4*)(Tp + c0);
        uint4 su = *(const uint4*)(Sp + c0);
        unsigned tw[4] = {tu.x, tu.y, tu.z, tu.w};
        unsigned swd[4] = {su.x, su.y, su.z, su.w};
        float hv[8];
#pragma unroll
        for (int p = 0; p < 4; ++p) {
            int j0 = 2 * p;
            float t0 = bf2f(tw[p]), t1 = bf2f(tw[p] >> 16);
            float s0 = bf2f(swd[p]), s1 = bf2f(swd[p] >> 16);
            float a = t0 + s0 + at0 * sw1a[c0 + j0] + at1 * sw1a[128 + c0 + j0] + at2 * sw1a[256 + c0 + j0];
            hv[j0] = fmaxf(a, 0.f);
            float b = t1 + s1 + at0 * sw1a[c0 + j0 + 1] + at1 * sw1a[128 + c0 + j0 + 1] + at2 * sw1a[256 + c0 + j0 + 1];
            hv[j0 + 1] = fmaxf(b, 0.f);
        }
        bf8 bfr;
        unsigned* bu = (unsigned*)&bfr;
#pragma unroll
        for (int p = 0; p < 4; ++p)
            asm("v_cvt_pk_bf16_f32 %0, %1, %2" : "=v"(bu[p]) : "v"(hv[2 * p]), "v"(hv[2 * p + 1]));
#pragma unroll
        for (int m = 0; m < 8; ++m)
            acc2[m] = __builtin_amdgcn_mfma_f32_16x16x32_bf16(
                *(const bf8*)(sW2 + ((m * 4 + kc2) * 64 + lane) * 8), bfr, acc2[m], 0, 0, 0);
    }

    // ---------- bias2 + LayerNorm ----------
    float o[8][4];
    float s = 0.f, q = 0.f;
#pragma unroll
    for (int m = 0; m < 8; ++m) {
        f4 bb = *(const f4*)(b2 + m * 16 + 4 * g);
#pragma unroll
        for (int r = 0; r < 4; ++r) {
            float v = acc2[m][r] + bb[r];
            o[m][r] = v; s += v; q += v * v;
        }
    }
    s += __shfl_xor(s, 16, 64); q += __shfl_xor(q, 16, 64);
    s += __shfl_xor(s, 32, 64); q += __shfl_xor(q, 32, 64);
    const float mean = s * (1.f / 128.f);
    const float inv = rsqrtf(q * (1.f / 128.f) - mean * mean + 1e-5f);

    // ---------- pack normalized msg into registers (zeros for invalid edges) ----------
    unsigned pm[8][2];
#pragma unroll
    for (int m = 0; m < 8; ++m) {
        f4 gg = *(const f4*)(gamma + m * 16 + 4 * g);
        f4 be4 = *(const f4*)(beta + m * 16 + 4 * g);
        float v0 = valid ? ((o[m][0] - mean) * inv * gg[0] + be4[0]) : 0.f;
        float v1 = valid ? ((o[m][1] - mean) * inv * gg[1] + be4[1]) : 0.f;
        float v2 = valid ? ((o[m][2] - mean) * inv * gg[2] + be4[2]) : 0.f;
        float v3 = valid ? ((o[m][3] - mean) * inv * gg[3] + be4[3]) : 0.f;
        asm("v_cvt_pk_bf16_f32 %0, %1, %2" : "=v"(pm[m][0]) : "v"(v0), "v"(v1));
        asm("v_cvt_pk_bf16_f32 %0, %1, %2" : "=v"(pm[m][1]) : "v"(v2), "v"(v3));
    }

    // ---------- two-pass LDS stage + segmented reduction ----------
    const int myhalf = le >> 6;       // 0 or 1
    const int rloc = le & 63;
    const int c2 = lane;              // channel pair 2*c2, 2*c2+1
#pragma unroll
    for (int hh = 0; hh < 2; ++hh) {
        if (myhalf == hh) {
            const unsigned swz = (unsigned)((rloc & 7) << 3);
            unsigned* row = smsg + rloc * 64;
#pragma unroll
            for (int m = 0; m < 8; ++m) {
                unsigned d0 = ((unsigned)(m * 8 + 2 * g)) ^ swz;
                uint2 uu; uu.x = pm[m][0]; uu.y = pm[m][1];
                *(uint2*)(row + d0) = uu;
            }
        }
        __syncthreads();
        // wave wv reduces local rows [wv*8, wv*8+8) of this half
        float a0 = 0.f, a1 = 0.f;
        int cur = stgt[hh * 64 + wv * 8];
#pragma unroll
        for (int j = 0; j < 8; ++j) {
            int rl = wv * 8 + j;
            int tg = stgt[hh * 64 + rl];
            if (tg != cur) {
                if (cur >= 0) {
                    atomicAdd(&aggr[(size_t)cur * 128 + 2 * c2], a0);
                    atomicAdd(&aggr[(size_t)cur * 128 + 2 * c2 + 1], a1);
                }
                a0 = 0.f; a1 = 0.f; cur = tg;
            }
            unsigned u = smsg[rl * 64 + (c2 ^ ((rl & 7) << 3))];
            a0 += __uint_as_float(u << 16);
            a1 += __uint_as_float(u & 0xFFFF0000u);
        }
        if (cur >= 0) {
            atomicAdd(&aggr[(size_t)cur * 128 + 2 * c2], a0);
            atomicAdd(&aggr[(size_t)cur * 128 + 2 * c2 + 1], a1);
        }
        if (hh == 0) __syncthreads();
    }
}

// ================= node MLP (LDS weights); NEXT=1 also computes Tarr/Sarr(l+1) + zeroes aggr =====
template <int NEXT>
__global__ __launch_bounds__(1024, 4) void node_mfma(
    const short* __restrict__ hbf, const float* __restrict__ aggrf,
    const short* __restrict__ w1p, const short* __restrict__ w2p,
    const float* __restrict__ b1, const float* __restrict__ b2,
    const float* __restrict__ gamma, const float* __restrict__ beta,
    float* __restrict__ outp, short* __restrict__ hbfout,
    const short* __restrict__ wtsnext, const float* __restrict__ b1next,
    short* __restrict__ TarrO, short* __restrict__ SarrO,
    float* __restrict__ aggrZ, int nrows) {
    __shared__ __align__(16) short sW1[8 * 8 * 512];   // 64 KB
    __shared__ __align__(16) short sW2[8 * 4 * 512];   // 32 KB

    const int tid = threadIdx.x;
    for (int t = tid; t < 8 * 8 * 512 / 8; t += 1024) ((uint4*)sW1)[t] = ((const uint4*)w1p)[t];
    for (int t = tid; t < 8 * 4 * 512 / 8; t += 1024) ((uint4*)sW2)[t] = ((const uint4*)w2p)[t];
    __syncthreads();

    const int lane = tid & 63;
    const int wv = tid >> 6;
    const int g = lane >> 4;
    const int er = lane & 15;
    const int e = blockIdx.x * 256 + wv * 16 + er;
    const bool valid = e < nrows;
    const int eC = valid ? e : 0;

    const bf8* rT = (const bf8*)(hbf + (size_t)eC * H);
    const f4* ra = (const f4*)(aggrf + (size_t)eC * H);

    f4 acc1[8] = {};
#pragma unroll
    for (int kc = 0; kc < 4; ++kc) {
        bf8 b = rT[kc * 4 + g];
#pragma unroll
        for (int m = 0; m < 8; ++m)
            acc1[m] = __builtin_amdgcn_mfma_f32_16x16x32_bf16(
                *(const bf8*)(sW1 + ((m * 8 + kc) * 64 + lane) * 8), b, acc1[m], 0, 0, 0);
    }
#pragma unroll
    for (int kc = 4; kc < 8; ++kc) {
        f4 a0 = ra[(kc - 4) * 8 + g * 2];
        f4 a1 = ra[(kc - 4) * 8 + g * 2 + 1];
        bf8 b;
        unsigned* bu = (unsigned*)&b;
        asm("v_cvt_pk_bf16_f32 %0, %1, %2" : "=v"(bu[0]) : "v"(a0[0]), "v"(a0[1]));
        asm("v_cvt_pk_bf16_f32 %0, %1, %2" : "=v"(bu[1]) : "v"(a0[2]), "v"(a0[3]));
        asm("v_cvt_pk_bf16_f32 %0, %1, %2" : "=v"(bu[2]) : "v"(a1[0]), "v"(a1[1]));
        asm("v_cvt_pk_bf16_f32 %0, %1, %2" : "=v"(bu[3]) : "v"(a1[2]), "v"(a1[3]));
#pragma unroll
        for (int m = 0; m < 8; ++m)
            acc1[m] = __builtin_amdgcn_mfma_f32_16x16x32_bf16(
                *(const bf8*)(sW1 + ((m * 8 + kc) * 64 + lane) * 8), b, acc1[m], 0, 0, 0);
    }

    float h1[8][4];
#pragma unroll
    for (int m = 0; m < 8; ++m) {
        f4 bb = *(const f4*)(b1 + m * 16 + 4 * g);
#pragma unroll
        for (int r = 0; r < 4; ++r) h1[m][r] = fmaxf(acc1[m][r] + bb[r], 0.f);
    }

    unsigned pk[8][2];
#pragma unroll
    for (int m = 0; m < 8; ++m)
#pragma unroll
        for (int hh = 0; hh < 2; ++hh)
            asm("v_cvt_pk_bf16_f32 %0, %1, %2"
                : "=v"(pk[m][hh]) : "v"(h1[m][2 * hh]), "v"(h1[m][2 * hh + 1]));

    f4 acc2[8] = {};
#pragma unroll
    for (int kc2 = 0; kc2 < 4; ++kc2) {
        bf8 bfr;
        unsigned* bu = (unsigned*)&bfr;
#pragma unroll
        for (int p = 0; p < 4; ++p) {
            int sl = er + 16 * (2 * (g & 1) + (p >> 1));
            unsigned lo = (unsigned)__shfl((int)pk[2 * kc2 + 0][p & 1], sl, 64);
            unsigned hi = (unsigned)__shfl((int)pk[2 * kc2 + 1][p & 1], sl, 64);
            bu[p] = (g >> 1) ? hi : lo;
        }
#pragma unroll
        for (int m = 0; m < 8; ++m)
            acc2[m] = __builtin_amdgcn_mfma_f32_16x16x32_bf16(
                *(const bf8*)(sW2 + ((m * 4 + kc2) * 64 + lane) * 8), bfr, acc2[m], 0, 0, 0);
    }

    float o[8][4];
    float s = 0.f, q = 0.f;
#pragma unroll
    for (int m = 0; m < 8; ++m) {
        f4 bb = *(const f4*)(b2 + m * 16 + 4 * g);
#pragma unroll
        for (int r = 0; r < 4; ++r) {
            float v = acc2[m][r] + bb[r];
            o[m][r] = v; s += v; q += v * v;
        }
    }
    s += __shfl_xor(s, 16, 64); q += __shfl_xor(q, 16, 64);
    s += __shfl_xor(s, 32, 64); q += __shfl_xor(q, 32, 64);
    const float mean = s * (1.f / 128.f);
    const float inv = rsqrtf(q * (1.f / 128.f) - mean * mean + 1e-5f);

    // ---------- residual epilogue; keep packed new-h in registers for NEXT ----------
    float* hp = outp + (size_t)eC * H;
    short* hb = hbfout + (size_t)eC * H;
    unsigned pkh[8][2];
#pragma unroll
    for (int m = 0; m < 8; ++m) {
        f4 gg = *(const f4*)(gamma + m * 16 + 4 * g);
        f4 be4 = *(const f4*)(beta + m * 16 + 4 * g);
        f4 hv;
        if (valid) hv = *(const f4*)(hp + m * 16 + 4 * g);
        else hv = f4{0.f, 0.f, 0.f, 0.f};
        f4 nv;
#pragma unroll
        for (int r = 0; r < 4; ++r)
            nv[r] = hv[r] + (o[m][r] - mean) * inv * gg[r] + be4[r];
        asm("v_cvt_pk_bf16_f32 %0, %1, %2" : "=v"(pkh[m][0]) : "v"(nv[0]), "v"(nv[1]));
        asm("v_cvt_pk_bf16_f32 %0, %1, %2" : "=v"(pkh[m][1]) : "v"(nv[2]), "v"(nv[3]));
        if (valid) {
            *(f4*)(hp + m * 16 + 4 * g) = nv;
            if (NEXT) {
                uint2 uu; uu.x = pkh[m][0]; uu.y = pkh[m][1];
                *(uint2*)(hb + m * 16 + 4 * g) = uu;
            }
        }
    }

    if (NEXT) {
        // build TS B-frags from new h via the (verified) transpose shuffle
        bf8 bfrs[4];
#pragma unroll
        for (int kc = 0; kc < 4; ++kc) {
            unsigned* bu = (unsigned*)&bfrs[kc];
#pragma unroll
            for (int p = 0; p < 4; ++p) {
                int sl = er + 16 * (2 * (g & 1) + (p >> 1));
                unsigned lo = (unsigned)__shfl((int)pkh[2 * kc + 0][p & 1], sl, 64);
                unsigned hi = (unsigned)__shfl((int)pkh[2 * kc + 1][p & 1], sl, 64);
                bu[p] = (g >> 1) ? hi : lo;
            }
        }
        const bf8* wN = (const bf8*)wtsnext + lane;
        // T half (m = 0..7), bias b1next
        f4 accT[8] = {};
#pragma unroll
        for (int kc = 0; kc < 4; ++kc)
#pragma unroll
            for (int m = 0; m < 8; ++m)
                accT[m] = __builtin_amdgcn_mfma_f32_16x16x32_bf16(
                    wN[(m * 4 + kc) * 64], bfrs[kc], accT[m], 0, 0, 0);
        if (valid) {
            short* oT = TarrO + (size_t)eC * 128;
            float* oZ = aggrZ + (size_t)eC * 128;
            const f4 zz = {0.f, 0.f, 0.f, 0.f};
#pragma unroll
            for (int m = 0; m < 8; ++m) {
                f4 bb = *(const f4*)(b1next + m * 16 + 4 * g);
                f4 v = accT[m] + bb;
                unsigned p0, p1;
                asm("v_cvt_pk_bf16_f32 %0, %1, %2" : "=v"(p0) : "v"(v[0]), "v"(v[1]));
                asm("v_cvt_pk_bf16_f32 %0, %1, %2" : "=v"(p1) : "v"(v[2]), "v"(v[3]));
                uint2 uu; uu.x = p0; uu.y = p1;
                *(uint2*)(oT + m * 16 + 4 * g) = uu;
                *(f4*)(oZ + m * 16 + 4 * g) = zz;   // zero aggr for next layer
            }
        }
        // S half (m = 8..15), no bias
        f4 accS[8] = {};
#pragma unroll
        for (int kc = 0; kc < 4; ++kc)
#pragma unroll
            for (int m = 0; m < 8; ++m)
                accS[m] = __builtin_amdgcn_mfma_f32_16x16x32_bf16(
                    wN[((m + 8) * 4 + kc) * 64], bfrs[kc], accS[m], 0, 0, 0);
        if (valid) {
            short* oS = SarrO + (size_t)eC * 128;
#pragma unroll
            for (int m = 0; m < 8; ++m) {
                f4 v = accS[m];
                unsigned p0, p1;
                asm("v_cvt_pk_bf16_f32 %0, %1, %2" : "=v"(p0) : "v"(v[0]), "v"(v[1]));
                asm("v_cvt_pk_bf16_f32 %0, %1, %2" : "=v"(p1) : "v"(v[2]), "v"(v[3]));
                uint2 uu; uu.x = p0; uu.y = p1;
                *(uint2*)(oS + m * 16 + 4 * g) = uu;
            }
        }
    }
}

// ================= fp32 ENC / DEC (small) =================
enum { MODE_ENC = 0, MODE_DEC = 3 };

__device__ __forceinline__ void fma_row(float acc[4], float a, const float4& b) {
    acc[0] = fmaf(a, b.x, acc[0]);
    acc[1] = fmaf(a, b.y, acc[1]);
    acc[2] = fmaf(a, b.z, acc[2]);
    acc[3] = fmaf(a, b.w, acc[3]);
}

__device__ __forceinline__ void gemm_seg(const float (*A)[LPAD], int K,
                                         const float* __restrict__ B,
                                         int row0, int c0, float acc[8][4]) {
    int k = 0;
    for (; k + 4 <= K; k += 4) {
        float4 b0 = *(const float4*)(B + (size_t)(k + 0) * H + c0);
        float4 b1 = *(const float4*)(B + (size_t)(k + 1) * H + c0);
        float4 b2 = *(const float4*)(B + (size_t)(k + 2) * H + c0);
        float4 b3 = *(const float4*)(B + (size_t)(k + 3) * H + c0);
#pragma unroll
        for (int j = 0; j < 8; ++j) {
            float4 a = *(const float4*)(&A[row0 + j][k]);
            fma_row(acc[j], a.x, b0);
            fma_row(acc[j], a.y, b1);
            fma_row(acc[j], a.z, b2);
            fma_row(acc[j], a.w, b3);
        }
    }
    for (; k < K; ++k) {
        float4 bv = *(const float4*)(B + (size_t)k * H + c0);
#pragma unroll
        for (int j = 0; j < 8; ++j) fma_row(acc[j], A[row0 + j][k], bv);
    }
}

template <int MODE>
__global__ __launch_bounds__(256, 2) void mlp_small(
    const float* __restrict__ in0,
    const float* __restrict__ w1, const float* __restrict__ b1,
    const float* __restrict__ w2, const float* __restrict__ b2,
    const float* __restrict__ g, const float* __restrict__ be,
    float* __restrict__ outp, short* __restrict__ hbfout, int nrows) {
    __shared__ __align__(16) float sA[BM][LPAD];

    const int tid = threadIdx.x;
    const int tr = tid >> 5, tc = tid & 31;
    const int c0 = tc * 4, row0 = tr * 8;
    const int r0 = blockIdx.x * BM;

    if (MODE == MODE_ENC) {
        for (int idx = tid; idx < BM * 10; idx += 256) {
            int r = idx / 10, c = idx - 10 * (idx / 10);
            int n = r0 + r;
            sA[r][c] = (n < nrows) ? in0[(size_t)n * 10 + c] : 0.f;
        }
    } else {
        for (int idx = tid; idx < BM * 32; idx += 256) {
            int r = idx >> 5, qq = idx & 31;
            int n = r0 + r;
            float4 v0 = make_float4(0.f, 0.f, 0.f, 0.f);
            if (n < nrows) v0 = ((const float4*)in0)[(size_t)n * 32 + qq];
            *(float4*)&sA[r][qq * 4] = v0;
        }
    }
    __syncthreads();

    float acc[8][4];
    {
        float4 bb = *(const float4*)&b1[c0];
#pragma unroll
        for (int j = 0; j < 8; ++j) { acc[j][0] = bb.x; acc[j][1] = bb.y; acc[j][2] = bb.z; acc[j][3] = bb.w; }
    }
    gemm_seg(sA, (MODE == MODE_ENC) ? 10 : H, w1, row0, c0, acc);
#pragma unroll
    for (int j = 0; j < 8; ++j)
#pragma unroll
        for (int r = 0; r < 4; ++r) acc[j][r] = fmaxf(acc[j][r], 0.f);

    __syncthreads();
#pragma unroll
    for (int j = 0; j < 8; ++j)
        *(float4*)&sA[row0 + j][c0] = make_float4(acc[j][0], acc[j][1], acc[j][2], acc[j][3]);
    __syncthreads();

    if (MODE == MODE_DEC) {
        if (tid < BM * 3) {
            int r = tid / 3, o = tid - 3 * (tid / 3);
            int gr = r0 + r;
            float sv = b2[o];
            for (int i = 0; i < H; ++i) sv = fmaf(sA[r][i], w2[(size_t)i * 3 + o], sv);
            if (gr < nrows) outp[(size_t)gr * 3 + o] = sv;
        }
        return;
    }

    {
        float4 bb = *(const float4*)&b2[c0];
#pragma unroll
        for (int j = 0; j < 8; ++j) { acc[j][0] = bb.x; acc[j][1] = bb.y; acc[j][2] = bb.z; acc[j][3] = bb.w; }
    }
    gemm_seg(sA, H, w2, row0, c0, acc);

    float4 g4 = *(const float4*)&g[c0];
    float4 be4 = *(const float4*)&be[c0];
#pragma unroll
    for (int j = 0; j < 8; ++j) {
        float s = acc[j][0] + acc[j][1] + acc[j][2] + acc[j][3];
        float q = acc[j][0] * acc[j][0] + acc[j][1] * acc[j][1] +
                  acc[j][2] * acc[j][2] + acc[j][3] * acc[j][3];
#pragma unroll
        for (int m = 1; m < 32; m <<= 1) { s += __shfl_xor(s, m); q += __shfl_xor(q, m); }
        float mean = s * (1.0f / 128.0f);
        float inv = rsqrtf(q * (1.0f / 128.0f) - mean * mean + 1e-5f);
        int gr = r0 + row0 + j;
        if (gr >= nrows) continue;
        float v0 = (acc[j][0] - mean) * inv * g4.x + be4.x;
        float v1 = (acc[j][1] - mean) * inv * g4.y + be4.y;
        float v2 = (acc[j][2] - mean) * inv * g4.z + be4.z;
        float v3 = (acc[j][3] - mean) * inv * g4.w + be4.w;
        *(float4*)&outp[(size_t)gr * H + c0] = make_float4(v0, v1, v2, v3);
        s4 pk = {f2bf(v0), f2bf(v1), f2bf(v2), f2bf(v3)};
        *(s4*)&hbfout[(size_t)gr * H + c0] = pk;
    }
}

// ================= launcher =================
static inline size_t align16(size_t x) { return (x + 15) & ~(size_t)15; }

extern "C" void kernel_launch(void* const* d_in, const int* in_sizes, int n_in,
                              void* d_out, int out_size, void* d_ws, size_t ws_size,
                              hipStream_t stream) {
    const float* x       = (const float*)d_in[0];
    const int*   ei      = (const int*)d_in[1];
    const float* eattr   = (const float*)d_in[2];
    const float* enc_w1  = (const float*)d_in[3];
    const float* enc_b1  = (const float*)d_in[4];
    const float* enc_w2  = (const float*)d_in[5];
    const float* enc_b2  = (const float*)d_in[6];
    const float* enc_g   = (const float*)d_in[7];
    const float* enc_be  = (const float*)d_in[8];
    const float* edge_w1 = (const float*)d_in[9];
    const float* edge_b1 = (const float*)d_in[10];
    const float* edge_w2 = (const float*)d_in[11];
    const float* edge_b2 = (const float*)d_in[12];
    const float* edge_g  = (const float*)d_in[13];
    const float* edge_be = (const float*)d_in[14];
    const float* node_w1 = (const float*)d_in[15];
    const float* node_b1 = (const float*)d_in[16];
    const float* node_w2 = (const float*)d_in[17];
    const float* node_b2 = (const float*)d_in[18];
    const float* node_g  = (const float*)d_in[19];
    const float* node_be = (const float*)d_in[20];
    const float* dec_w1  = (const float*)d_in[21];
    const float* dec_b1  = (const float*)d_in[22];
    const float* dec_w2  = (const float*)d_in[23];
    const float* dec_b2  = (const float*)d_in[24];

    const int N = in_sizes[0] / 10;
    const int E = in_sizes[1] / 2;
    const int* srcI = ei;
    const int* tgtI = ei + E;

    // ---- workspace layout (~106 MB) ----
    char* base = (char*)d_ws;
    size_t off = 0;
    float* h     = (float*)(base + off); off = align16(off + (size_t)N * H * 4);
    float* aggr  = (float*)(base + off); off = align16(off + (size_t)N * H * 4);
    short* hbf   = (short*)(base + off); off = align16(off + (size_t)N * H * 2);
    short* Tarr  = (short*)(base + off); off = align16(off + (size_t)N * H * 2);
    short* Sarr  = (short*)(base + off); off = align16(off + (size_t)N * H * 2);
    short* attrb = (short*)(base + off); off = align16(off + (size_t)E * 4 * 2);
    short* ewtsp = (short*)(base + off); off = align16(off + (size_t)4 * 16 * 4 * 512 * 2);
    short* ew2p  = (short*)(base + off); off = align16(off + (size_t)4 * 8 * 4 * 512 * 2);
    short* nw1p  = (short*)(base + off); off = align16(off + (size_t)4 * 8 * 8 * 512 * 2);
    short* nw2p  = (short*)(base + off); off = align16(off + (size_t)4 * 8 * 4 * 512 * 2);
    int*   cnt   = (int*)(base + off);  off = align16(off + (size_t)N * 4);
    int*   startp= (int*)(base + off);  off = align16(off + (size_t)(N + 1) * 4);
    int2*  stpair= (int2*)(base + off); off = align16(off + (size_t)E * 8);

    // ---- one-time packs ----
    pack_wts<<<dim3(64, 1, 4), 256, 0, stream>>>(edge_w1, ewtsp);
    pack_w<<<dim3(32, 1, 4), 256, 0, stream>>>(edge_w2, ew2p, H, 4);
    pack_w<<<dim3(64, 1, 4), 256, 0, stream>>>(node_w1, nw1p, 2 * H, 8);
    pack_w<<<dim3(32, 1, 4), 256, 0, stream>>>(node_w2, nw2p, H, 4);

    // ---- CSR build + tgt-sorted edge arrays ----
    hipMemsetAsync(cnt, 0, (size_t)N * 4, stream);
    csr_count<<<(E + 255) / 256, 256, 0, stream>>>(tgtI, cnt, E);
    scan_excl<<<1, SCAN_T, 0, stream>>>(cnt, startp, N);
    csr_scatter_reorder<<<(E + 255) / 256, 256, 0, stream>>>(
        tgtI, srcI, eattr, startp, stpair, attrb, E);

    const int gN64 = (N + BM - 1) / BM;
    mlp_small<MODE_ENC><<<gN64, 256, 0, stream>>>(
        x, enc_w1, enc_b1, enc_w2, enc_b2, enc_g, enc_be, h, hbf, N);

    const int gTS = (N + 127) / 128;
    const int gEe = (E + 127) / 128;
    const int gNN = (N + 255) / 256;

    // ts for layer 0 (also zeroes aggr)
    ts_mfma<<<gTS, 512, 0, stream>>>(
        hbf, ewtsp, edge_b1, Tarr, Sarr, aggr, N);

    for (int l = 0; l < 4; ++l) {
        const float* w1aG = edge_w1 + (size_t)l * 259 * 128 + 256 * 128;
        edge_fused<<<gEe, 512, 0, stream>>>(
            Tarr, Sarr, attrb, stpair, ew2p + (size_t)l * 8 * 4 * 512, w1aG,
            edge_b2 + (size_t)l * H, edge_g + (size_t)l * H, edge_be + (size_t)l * H,
            aggr, E);
        if (l < 3) {
            node_mfma<1><<<gNN, 1024, 0, stream>>>(
                hbf, aggr,
                nw1p + (size_t)l * 8 * 8 * 512, nw2p + (size_t)l * 8 * 4 * 512,
                node_b1 + (size_t)l * H, node_b2 + (size_t)l * H,
                node_g + (size_t)l * H, node_be + (size_t)l * H,
                h, hbf,
                ewtsp + (size_t)(l + 1) * 16 * 4 * 512, edge_b1 + (size_t)(l + 1) * H,
                Tarr, Sarr, aggr, N);
        } else {
            node_mfma<0><<<gNN, 1024, 0, stream>>>(
                hbf, aggr,
                nw1p + (size_t)l * 8 * 8 * 512, nw2p + (size_t)l * 8 * 4 * 512,
                node_b1 + (size_t)l * H, node_b2 + (size_t)l * H,
                node_g + (size_t)l * H, node_be + (size_t)l * H,
                h, hbf,
                nullptr, nullptr, nullptr, nullptr, nullptr, N);
        }
    }

    mlp_small<MODE_DEC><<<gN64, 256, 0, stream>>>(
        h, dec_w1, dec_b1, dec_w2, dec_b2, nullptr, nullptr, (float*)d_out, nullptr, N);
}

// Round 12
// 791.638 us; speedup vs baseline: 1.1315x; 1.1315x over previous
//
#include <hip/hip_runtime.h>

#define H 128
#define LPAD 132
#define BM 64

typedef __attribute__((ext_vector_type(8))) short bf8;
typedef __attribute__((ext_vector_type(4))) float f4;
typedef __attribute__((ext_vector_type(4))) short s4;

__device__ __forceinline__ short f2bf(float f) {
    unsigned u = __float_as_uint(f);
    unsigned r = u + 0x7FFFu + ((u >> 16) & 1u);   // round-to-nearest-even
    return (short)(r >> 16);
}
__device__ __forceinline__ float bf2f(unsigned lo16) {
    return __uint_as_float((lo16 & 0xFFFFu) << 16);
}

// ================= weight packing =================
// packed[m][kc][lane][i] = bf16( W[kc*32 + (lane>>4)*8 + i][m*16 + (lane&15)] ), 0 if k>=K
__global__ void pack_w(const float* __restrict__ W, short* __restrict__ out, int K, int KC) {
    const int layer = blockIdx.z;
    const float* Wl = W + (size_t)layer * K * H;
    short* ol = out + (size_t)layer * 8 * KC * 512;
    const int total = 8 * KC * 512;
    for (int idx = blockIdx.x * blockDim.x + threadIdx.x; idx < total; idx += gridDim.x * blockDim.x) {
        int i = idx & 7;
        int lane = (idx >> 3) & 63;
        int v = idx >> 9;
        int kc = v % KC;
        int m = v / KC;
        int k = kc * 32 + (lane >> 4) * 8 + i;
        int c = m * 16 + (lane & 15);
        float val = (k < K) ? Wl[(size_t)k * H + c] : 0.f;
        ol[idx] = f2bf(val);
    }
}

// TS weights: c'<128 -> edge_w1[l][k][c'] (tgt), c'>=128 -> edge_w1[l][128+k][c'-128] (src)
__global__ void pack_wts(const float* __restrict__ W /*[L][259][128]*/, short* __restrict__ out) {
    const int layer = blockIdx.z;
    const float* Wl = W + (size_t)layer * 259 * 128;
    short* ol = out + (size_t)layer * 16 * 4 * 512;
    const int total = 16 * 4 * 512;
    for (int idx = blockIdx.x * blockDim.x + threadIdx.x; idx < total; idx += gridDim.x * blockDim.x) {
        int i = idx & 7;
        int lane = (idx >> 3) & 63;
        int v = idx >> 9;
        int kc = v & 3;
        int m = v >> 2;
        int k = kc * 32 + (lane >> 4) * 8 + i;
        int c = m * 16 + (lane & 15);     // 0..255
        float val = (c < 128) ? Wl[(size_t)k * 128 + c] : Wl[(size_t)(128 + k) * 128 + (c - 128)];
        ol[idx] = f2bf(val);
    }
}

// ================= CSR build =================
__global__ void csr_count(const int* __restrict__ tgt, int* __restrict__ cnt, int E) {
    int e = blockIdx.x * blockDim.x + threadIdx.x;
    if (e < E) atomicAdd(&cnt[tgt[e]], 1);
}

#define SCAN_T 1024
__global__ __launch_bounds__(SCAN_T) void scan_excl(const int* __restrict__ cnt,
                                                    int* __restrict__ start, int n) {
    __shared__ int part[SCAN_T];
    int t = threadIdx.x;
    int chunk = (n + SCAN_T - 1) / SCAN_T;
    int lo = t * chunk, hi = min(lo + chunk, n);
    int s = 0;
    for (int i = lo; i < hi; ++i) s += cnt[i];
    part[t] = s;
    __syncthreads();
    for (int off = 1; off < SCAN_T; off <<= 1) {
        int v = (t >= off) ? part[t - off] : 0;
        __syncthreads();
        part[t] += v;
        __syncthreads();
    }
    int base = (t > 0) ? part[t - 1] : 0;
    for (int i = lo; i < hi; ++i) { start[i] = base; base += cnt[i]; }
}

// scatter + reorder fused: sorted position p gets edge e's (src,tgt) pair + attr ([E][4] bf16)
__global__ void csr_scatter_reorder(const int* __restrict__ tgtI, const int* __restrict__ srcI,
                                    const float* __restrict__ eattr,
                                    int* __restrict__ start,
                                    int2* __restrict__ stpair,
                                    short* __restrict__ attrb, int E) {
    int e = blockIdx.x * blockDim.x + threadIdx.x;
    if (e >= E) return;
    int t = tgtI[e];
    int p = atomicAdd(&start[t], 1);
    stpair[p] = make_int2(srcI[e], t);
    s4 vv = {};
    vv[0] = f2bf(eattr[(size_t)e * 3 + 0]);
    vv[1] = f2bf(eattr[(size_t)e * 3 + 1]);
    vv[2] = f2bf(eattr[(size_t)e * 3 + 2]);
    *(s4*)(attrb + (size_t)p * 4) = vv;
}

// ========== TS precompute (layer 0 only): Tarr/Sarr bf16 + fused aggr zeroing ==========
__global__ __launch_bounds__(512, 4) void ts_mfma(
    const short* __restrict__ hbf, const short* __restrict__ wtsp,
    const float* __restrict__ b1,
    short* __restrict__ Tarr, short* __restrict__ Sarr,
    float* __restrict__ aggr, int N) {
    __shared__ __align__(16) short sW[16 * 4 * 512];   // 64 KB
    const int tid = threadIdx.x;
    for (int t = tid; t < 16 * 4 * 512 / 8; t += 512) ((uint4*)sW)[t] = ((const uint4*)wtsp)[t];
    __syncthreads();

    const int lane = tid & 63;
    const int wv = tid >> 6;          // 0..7
    const int g = lane >> 4;
    const int er = lane & 15;
    const int n = blockIdx.x * 128 + wv * 16 + er;
    const int nC = (n < N) ? n : 0;
    const bf8* rT = (const bf8*)(hbf + (size_t)nC * H);

    f4 acc[16] = {};
#pragma unroll
    for (int kc = 0; kc < 4; ++kc) {
        bf8 b = rT[kc * 4 + g];
#pragma unroll
        for (int m = 0; m < 16; ++m)
            acc[m] = __builtin_amdgcn_mfma_f32_16x16x32_bf16(
                *(const bf8*)(sW + ((m * 4 + kc) * 64 + lane) * 8), b, acc[m], 0, 0, 0);
    }
    if (n >= N) return;
    short* oT = Tarr + (size_t)n * 128;
    short* oS = Sarr + (size_t)n * 128;
    float* oZ = aggr + (size_t)n * 128;
    const f4 zz = {0.f, 0.f, 0.f, 0.f};
#pragma unroll
    for (int m = 0; m < 16; ++m) {
        f4 v = acc[m];
        if (m < 8) {
            f4 bb = *(const f4*)(b1 + m * 16 + 4 * g);
            v = v + bb;
            *(f4*)(oZ + m * 16 + 4 * g) = zz;   // fused aggr zeroing
        }
        unsigned p0, p1;
        asm("v_cvt_pk_bf16_f32 %0, %1, %2" : "=v"(p0) : "v"(v[0]), "v"(v[1]));
        asm("v_cvt_pk_bf16_f32 %0, %1, %2" : "=v"(p1) : "v"(v[2]), "v"(v[3]));
        uint2 uu; uu.x = p0; uu.y = p1;
        if (m < 8) *(uint2*)(oT + m * 16 + 4 * g) = uu;
        else       *(uint2*)(oS + (m - 8) * 16 + 4 * g) = uu;
    }
}

// ================= fused edge kernel (128 edges / 512 threads, single-pass smsg) =================
// hid = relu(T[tgt]+S[src]+attr*W1a); msg = LN(hid@W2+b2) -> LDS (own-wave rows) ->
// intra-wave fence (NO block barrier) -> segmented sum -> atomicAdd aggr
__global__ __launch_bounds__(512, 4) void edge_fused(
    const short* __restrict__ Tarr, const short* __restrict__ Sarr,
    const short* __restrict__ attrbf,
    const int2* __restrict__ stpair,
    const short* __restrict__ w2p,
    const float* __restrict__ w1aG,   // [3][128] f32 (attr rows of edge_w1)
    const float* __restrict__ b2,
    const float* __restrict__ gamma, const float* __restrict__ beta,
    float* __restrict__ aggr, int nrows) {
    __shared__ __align__(16) short sW2[8 * 4 * 512];     // 32 KB
    __shared__ float sw1a[3 * 128];                      // 1.5 KB
    __shared__ __align__(16) unsigned smsg[128 * 64];    // 32 KB, [edge][dword] swizzled
    __shared__ int stgt[128];

    const int tid = threadIdx.x;
    for (int t = tid; t < 8 * 4 * 512 / 8; t += 512) ((uint4*)sW2)[t] = ((const uint4*)w2p)[t];
    if (tid < 384) sw1a[tid] = w1aG[tid];
    const int e0b = blockIdx.x * 128;
    if (tid < 128) {
        int ee = e0b + tid;
        stgt[tid] = (ee < nrows) ? stpair[ee].y : -1;
    }
    __syncthreads();

    const int lane = tid & 63;
    const int wv = tid >> 6;          // 0..7
    const int g = lane >> 4;
    const int er = lane & 15;
    const int le = wv * 16 + er;      // local edge 0..127
    const int e = e0b + le;
    const bool valid = e < nrows;
    const int eC = valid ? e : 0;
    const int2 st = stpair[eC];
    const int tS = st.x;
    const int tT = st.y;

    uint2 au = *(const uint2*)(attrbf + (size_t)eC * 4);
    const float at0 = bf2f(au.x), at1 = bf2f(au.x >> 16), at2 = bf2f(au.y);

    const short* Tp = Tarr + (size_t)tT * 128;
    const short* Sp = Sarr + (size_t)tS * 128;

    // ---------- hid build + GEMM2 ----------
    f4 acc2[8] = {};
#pragma unroll
    for (int kc2 = 0; kc2 < 4; ++kc2) {
        const int c0 = kc2 * 32 + 8 * g;
        uint4 tu = *(const uint4*)(Tp + c0);
        uint4 su = *(const uint4*)(Sp + c0);
        unsigned tw[4] = {tu.x, tu.y, tu.z, tu.w};
        unsigned swd[4] = {su.x, su.y, su.z, su.w};
        float hv[8];
#pragma unroll
        for (int p = 0; p < 4; ++p) {
            int j0 = 2 * p;
            float t0 = bf2f(tw[p]), t1 = bf2f(tw[p] >> 16);
            float s0 = bf2f(swd[p]), s1 = bf2f(swd[p] >> 16);
            float a = t0 + s0 + at0 * sw1a[c0 + j0] + at1 * sw1a[128 + c0 + j0] + at2 * sw1a[256 + c0 + j0];
            hv[j0] = fmaxf(a, 0.f);
            float b = t1 + s1 + at0 * sw1a[c0 + j0 + 1] + at1 * sw1a[128 + c0 + j0 + 1] + at2 * sw1a[256 + c0 + j0 + 1];
            hv[j0 + 1] = fmaxf(b, 0.f);
        }
        bf8 bfr;
        unsigned* bu = (unsigned*)&bfr;
#pragma unroll
        for (int p = 0; p < 4; ++p)
            asm("v_cvt_pk_bf16_f32 %0, %1, %2" : "=v"(bu[p]) : "v"(hv[2 * p]), "v"(hv[2 * p + 1]));
#pragma unroll
        for (int m = 0; m < 8; ++m)
            acc2[m] = __builtin_amdgcn_mfma_f32_16x16x32_bf16(
                *(const bf8*)(sW2 + ((m * 4 + kc2) * 64 + lane) * 8), bfr, acc2[m], 0, 0, 0);
    }

    // ---------- bias2 + LayerNorm ----------
    float o[8][4];
    float s = 0.f, q = 0.f;
#pragma unroll
    for (int m = 0; m < 8; ++m) {
        f4 bb = *(const f4*)(b2 + m * 16 + 4 * g);
#pragma unroll
        for (int r = 0; r < 4; ++r) {
            float v = acc2[m][r] + bb[r];
            o[m][r] = v; s += v; q += v * v;
        }
    }
    s += __shfl_xor(s, 16, 64); q += __shfl_xor(q, 16, 64);
    s += __shfl_xor(s, 32, 64); q += __shfl_xor(q, 32, 64);
    const float mean = s * (1.f / 128.f);
    const float inv = rsqrtf(q * (1.f / 128.f) - mean * mean + 1e-5f);

    // ---------- write normalized msg to LDS (zeros for invalid edges) ----------
    const unsigned swz = (unsigned)((le & 7) << 3);
    unsigned* row = smsg + le * 64;
#pragma unroll
    for (int m = 0; m < 8; ++m) {
        f4 gg = *(const f4*)(gamma + m * 16 + 4 * g);
        f4 be4 = *(const f4*)(beta + m * 16 + 4 * g);
        float v0 = valid ? ((o[m][0] - mean) * inv * gg[0] + be4[0]) : 0.f;
        float v1 = valid ? ((o[m][1] - mean) * inv * gg[1] + be4[1]) : 0.f;
        float v2 = valid ? ((o[m][2] - mean) * inv * gg[2] + be4[2]) : 0.f;
        float v3 = valid ? ((o[m][3] - mean) * inv * gg[3] + be4[3]) : 0.f;
        unsigned p0, p1;
        asm("v_cvt_pk_bf16_f32 %0, %1, %2" : "=v"(p0) : "v"(v0), "v"(v1));
        asm("v_cvt_pk_bf16_f32 %0, %1, %2" : "=v"(p1) : "v"(v2), "v"(v3));
        unsigned d0 = ((unsigned)(m * 8 + 2 * g)) ^ swz;
        uint2 uu; uu.x = p0; uu.y = p1;
        *(uint2*)(row + d0) = uu;
    }
    // Wave wv only reads rows [wv*16, wv*16+16) below — written exclusively by this
    // wave's own lanes. Intra-wave LDS write->read needs only lgkmcnt(0), not s_barrier.
    asm volatile("s_waitcnt lgkmcnt(0)" ::: "memory");

    // ---------- segmented reduction (wave-local rows, wave-uniform control flow) ----------
    const int c2 = tid & 63;
    const int chunk = tid >> 6;       // == wv, 16 edges per chunk
    float a0 = 0.f, a1 = 0.f;
    int cur = stgt[chunk * 16];
    for (int j = 0; j < 16; ++j) {
        int le2 = chunk * 16 + j;
        int tg = stgt[le2];
        if (tg != cur) {
            if (cur >= 0) {
                atomicAdd(&aggr[(size_t)cur * 128 + 2 * c2], a0);
                atomicAdd(&aggr[(size_t)cur * 128 + 2 * c2 + 1], a1);
            }
            a0 = 0.f; a1 = 0.f; cur = tg;
        }
        unsigned u = smsg[le2 * 64 + (c2 ^ ((le2 & 7) << 3))];
        a0 += __uint_as_float(u << 16);
        a1 += __uint_as_float(u & 0xFFFF0000u);
    }
    if (cur >= 0) {
        atomicAdd(&aggr[(size_t)cur * 128 + 2 * c2], a0);
        atomicAdd(&aggr[(size_t)cur * 128 + 2 * c2 + 1], a1);
    }
}

// ================= node MLP (LDS weights); NEXT=1 also computes Tarr/Sarr(l+1) + zeroes aggr =====
template <int NEXT>
__global__ __launch_bounds__(1024, 4) void node_mfma(
    const short* __restrict__ hbf, const float* __restrict__ aggrf,
    const short* __restrict__ w1p, const short* __restrict__ w2p,
    const float* __restrict__ b1, const float* __restrict__ b2,
    const float* __restrict__ gamma, const float* __restrict__ beta,
    float* __restrict__ outp, short* __restrict__ hbfout,
    const short* __restrict__ wtsnext, const float* __restrict__ b1next,
    short* __restrict__ TarrO, short* __restrict__ SarrO,
    float* __restrict__ aggrZ, int nrows) {
    __shared__ __align__(16) short sW1[8 * 8 * 512];   // 64 KB
    __shared__ __align__(16) short sW2[8 * 4 * 512];   // 32 KB

    const int tid = threadIdx.x;
    for (int t = tid; t < 8 * 8 * 512 / 8; t += 1024) ((uint4*)sW1)[t] = ((const uint4*)w1p)[t];
    for (int t = tid; t < 8 * 4 * 512 / 8; t += 1024) ((uint4*)sW2)[t] = ((const uint4*)w2p)[t];
    __syncthreads();

    const int lane = tid & 63;
    const int wv = tid >> 6;
    const int g = lane >> 4;
    const int er = lane & 15;
    const int e = blockIdx.x * 256 + wv * 16 + er;
    const bool valid = e < nrows;
    const int eC = valid ? e : 0;

    const bf8* rT = (const bf8*)(hbf + (size_t)eC * H);
    const f4* ra = (const f4*)(aggrf + (size_t)eC * H);

    f4 acc1[8] = {};
#pragma unroll
    for (int kc = 0; kc < 4; ++kc) {
        bf8 b = rT[kc * 4 + g];
#pragma unroll
        for (int m = 0; m < 8; ++m)
            acc1[m] = __builtin_amdgcn_mfma_f32_16x16x32_bf16(
                *(const bf8*)(sW1 + ((m * 8 + kc) * 64 + lane) * 8), b, acc1[m], 0, 0, 0);
    }
#pragma unroll
    for (int kc = 4; kc < 8; ++kc) {
        f4 a0 = ra[(kc - 4) * 8 + g * 2];
        f4 a1 = ra[(kc - 4) * 8 + g * 2 + 1];
        bf8 b;
        unsigned* bu = (unsigned*)&b;
        asm("v_cvt_pk_bf16_f32 %0, %1, %2" : "=v"(bu[0]) : "v"(a0[0]), "v"(a0[1]));
        asm("v_cvt_pk_bf16_f32 %0, %1, %2" : "=v"(bu[1]) : "v"(a0[2]), "v"(a0[3]));
        asm("v_cvt_pk_bf16_f32 %0, %1, %2" : "=v"(bu[2]) : "v"(a1[0]), "v"(a1[1]));
        asm("v_cvt_pk_bf16_f32 %0, %1, %2" : "=v"(bu[3]) : "v"(a1[2]), "v"(a1[3]));
#pragma unroll
        for (int m = 0; m < 8; ++m)
            acc1[m] = __builtin_amdgcn_mfma_f32_16x16x32_bf16(
                *(const bf8*)(sW1 + ((m * 8 + kc) * 64 + lane) * 8), b, acc1[m], 0, 0, 0);
    }

    float h1[8][4];
#pragma unroll
    for (int m = 0; m < 8; ++m) {
        f4 bb = *(const f4*)(b1 + m * 16 + 4 * g);
#pragma unroll
        for (int r = 0; r < 4; ++r) h1[m][r] = fmaxf(acc1[m][r] + bb[r], 0.f);
    }

    unsigned pk[8][2];
#pragma unroll
    for (int m = 0; m < 8; ++m)
#pragma unroll
        for (int hh = 0; hh < 2; ++hh)
            asm("v_cvt_pk_bf16_f32 %0, %1, %2"
                : "=v"(pk[m][hh]) : "v"(h1[m][2 * hh]), "v"(h1[m][2 * hh + 1]));

    f4 acc2[8] = {};
#pragma unroll
    for (int kc2 = 0; kc2 < 4; ++kc2) {
        bf8 bfr;
        unsigned* bu = (unsigned*)&bfr;
#pragma unroll
        for (int p = 0; p < 4; ++p) {
            int sl = er + 16 * (2 * (g & 1) + (p >> 1));
            unsigned lo = (unsigned)__shfl((int)pk[2 * kc2 + 0][p & 1], sl, 64);
            unsigned hi = (unsigned)__shfl((int)pk[2 * kc2 + 1][p & 1], sl, 64);
            bu[p] = (g >> 1) ? hi : lo;
        }
#pragma unroll
        for (int m = 0; m < 8; ++m)
            acc2[m] = __builtin_amdgcn_mfma_f32_16x16x32_bf16(
                *(const bf8*)(sW2 + ((m * 4 + kc2) * 64 + lane) * 8), bfr, acc2[m], 0, 0, 0);
    }

    float o[8][4];
    float s = 0.f, q = 0.f;
#pragma unroll
    for (int m = 0; m < 8; ++m) {
        f4 bb = *(const f4*)(b2 + m * 16 + 4 * g);
#pragma unroll
        for (int r = 0; r < 4; ++r) {
            float v = acc2[m][r] + bb[r];
            o[m][r] = v; s += v; q += v * v;
        }
    }
    s += __shfl_xor(s, 16, 64); q += __shfl_xor(q, 16, 64);
    s += __shfl_xor(s, 32, 64); q += __shfl_xor(q, 32, 64);
    const float mean = s * (1.f / 128.f);
    const float inv = rsqrtf(q * (1.f / 128.f) - mean * mean + 1e-5f);

    // ---------- residual epilogue; keep packed new-h in registers for NEXT ----------
    float* hp = outp + (size_t)eC * H;
    short* hb = hbfout + (size_t)eC * H;
    unsigned pkh[8][2];
#pragma unroll
    for (int m = 0; m < 8; ++m) {
        f4 gg = *(const f4*)(gamma + m * 16 + 4 * g);
        f4 be4 = *(const f4*)(beta + m * 16 + 4 * g);
        f4 hv;
        if (valid) hv = *(const f4*)(hp + m * 16 + 4 * g);
        else hv = f4{0.f, 0.f, 0.f, 0.f};
        f4 nv;
#pragma unroll
        for (int r = 0; r < 4; ++r)
            nv[r] = hv[r] + (o[m][r] - mean) * inv * gg[r] + be4[r];
        asm("v_cvt_pk_bf16_f32 %0, %1, %2" : "=v"(pkh[m][0]) : "v"(nv[0]), "v"(nv[1]));
        asm("v_cvt_pk_bf16_f32 %0, %1, %2" : "=v"(pkh[m][1]) : "v"(nv[2]), "v"(nv[3]));
        if (valid) {
            *(f4*)(hp + m * 16 + 4 * g) = nv;
            if (NEXT) {
                uint2 uu; uu.x = pkh[m][0]; uu.y = pkh[m][1];
                *(uint2*)(hb + m * 16 + 4 * g) = uu;
            }
        }
    }

    if (NEXT) {
        // build TS B-frags from new h via the (verified) transpose shuffle
        bf8 bfrs[4];
#pragma unroll
        for (int kc = 0; kc < 4; ++kc) {
            unsigned* bu = (unsigned*)&bfrs[kc];
#pragma unroll
            for (int p = 0; p < 4; ++p) {
                int sl = er + 16 * (2 * (g & 1) + (p >> 1));
                unsigned lo = (unsigned)__shfl((int)pkh[2 * kc + 0][p & 1], sl, 64);
                unsigned hi = (unsigned)__shfl((int)pkh[2 * kc + 1][p & 1], sl, 64);
                bu[p] = (g >> 1) ? hi : lo;
            }
        }
        const bf8* wN = (const bf8*)wtsnext + lane;
        // T half (m = 0..7), bias b1next
        f4 accT[8] = {};
#pragma unroll
        for (int kc = 0; kc < 4; ++kc)
#pragma unroll
            for (int m = 0; m < 8; ++m)
                accT[m] = __builtin_amdgcn_mfma_f32_16x16x32_bf16(
                    wN[(m * 4 + kc) * 64], bfrs[kc], accT[m], 0, 0, 0);
        if (valid) {
            short* oT = TarrO + (size_t)eC * 128;
            float* oZ = aggrZ + (size_t)eC * 128;
            const f4 zz = {0.f, 0.f, 0.f, 0.f};
#pragma unroll
            for (int m = 0; m < 8; ++m) {
                f4 bb = *(const f4*)(b1next + m * 16 + 4 * g);
                f4 v = accT[m] + bb;
                unsigned p0, p1;
                asm("v_cvt_pk_bf16_f32 %0, %1, %2" : "=v"(p0) : "v"(v[0]), "v"(v[1]));
                asm("v_cvt_pk_bf16_f32 %0, %1, %2" : "=v"(p1) : "v"(v[2]), "v"(v[3]));
                uint2 uu; uu.x = p0; uu.y = p1;
                *(uint2*)(oT + m * 16 + 4 * g) = uu;
                *(f4*)(oZ + m * 16 + 4 * g) = zz;   // zero aggr for next layer
            }
        }
        // S half (m = 8..15), no bias
        f4 accS[8] = {};
#pragma unroll
        for (int kc = 0; kc < 4; ++kc)
#pragma unroll
            for (int m = 0; m < 8; ++m)
                accS[m] = __builtin_amdgcn_mfma_f32_16x16x32_bf16(
                    wN[((m + 8) * 4 + kc) * 64], bfrs[kc], accS[m], 0, 0, 0);
        if (valid) {
            short* oS = SarrO + (size_t)eC * 128;
#pragma unroll
            for (int m = 0; m < 8; ++m) {
                f4 v = accS[m];
                unsigned p0, p1;
                asm("v_cvt_pk_bf16_f32 %0, %1, %2" : "=v"(p0) : "v"(v[0]), "v"(v[1]));
                asm("v_cvt_pk_bf16_f32 %0, %1, %2" : "=v"(p1) : "v"(v[2]), "v"(v[3]));
                uint2 uu; uu.x = p0; uu.y = p1;
                *(uint2*)(oS + m * 16 + 4 * g) = uu;
            }
        }
    }
}

// ================= fp32 ENC / DEC (small) =================
enum { MODE_ENC = 0, MODE_DEC = 3 };

__device__ __forceinline__ void fma_row(float acc[4], float a, const float4& b) {
    acc[0] = fmaf(a, b.x, acc[0]);
    acc[1] = fmaf(a, b.y, acc[1]);
    acc[2] = fmaf(a, b.z, acc[2]);
    acc[3] = fmaf(a, b.w, acc[3]);
}

__device__ __forceinline__ void gemm_seg(const float (*A)[LPAD], int K,
                                         const float* __restrict__ B,
                                         int row0, int c0, float acc[8][4]) {
    int k = 0;
    for (; k + 4 <= K; k += 4) {
        float4 b0 = *(const float4*)(B + (size_t)(k + 0) * H + c0);
        float4 b1 = *(const float4*)(B + (size_t)(k + 1) * H + c0);
        float4 b2 = *(const float4*)(B + (size_t)(k + 2) * H + c0);
        float4 b3 = *(const float4*)(B + (size_t)(k + 3) * H + c0);
#pragma unroll
        for (int j = 0; j < 8; ++j) {
            float4 a = *(const float4*)(&A[row0 + j][k]);
            fma_row(acc[j], a.x, b0);
            fma_row(acc[j], a.y, b1);
            fma_row(acc[j], a.z, b2);
            fma_row(acc[j], a.w, b3);
        }
    }
    for (; k < K; ++k) {
        float4 bv = *(const float4*)(B + (size_t)k * H + c0);
#pragma unroll
        for (int j = 0; j < 8; ++j) fma_row(acc[j], A[row0 + j][k], bv);
    }
}

template <int MODE>
__global__ __launch_bounds__(256, 2) void mlp_small(
    const float* __restrict__ in0,
    const float* __restrict__ w1, const float* __restrict__ b1,
    const float* __restrict__ w2, const float* __restrict__ b2,
    const float* __restrict__ g, const float* __restrict__ be,
    float* __restrict__ outp, short* __restrict__ hbfout, int nrows) {
    __shared__ __align__(16) float sA[BM][LPAD];

    const int tid = threadIdx.x;
    const int tr = tid >> 5, tc = tid & 31;
    const int c0 = tc * 4, row0 = tr * 8;
    const int r0 = blockIdx.x * BM;

    if (MODE == MODE_ENC) {
        for (int idx = tid; idx < BM * 10; idx += 256) {
            int r = idx / 10, c = idx - 10 * (idx / 10);
            int n = r0 + r;
            sA[r][c] = (n < nrows) ? in0[(size_t)n * 10 + c] : 0.f;
        }
    } else {
        for (int idx = tid; idx < BM * 32; idx += 256) {
            int r = idx >> 5, qq = idx & 31;
            int n = r0 + r;
            float4 v0 = make_float4(0.f, 0.f, 0.f, 0.f);
            if (n < nrows) v0 = ((const float4*)in0)[(size_t)n * 32 + qq];
            *(float4*)&sA[r][qq * 4] = v0;
        }
    }
    __syncthreads();

    float acc[8][4];
    {
        float4 bb = *(const float4*)&b1[c0];
#pragma unroll
        for (int j = 0; j < 8; ++j) { acc[j][0] = bb.x; acc[j][1] = bb.y; acc[j][2] = bb.z; acc[j][3] = bb.w; }
    }
    gemm_seg(sA, (MODE == MODE_ENC) ? 10 : H, w1, row0, c0, acc);
#pragma unroll
    for (int j = 0; j < 8; ++j)
#pragma unroll
        for (int r = 0; r < 4; ++r) acc[j][r] = fmaxf(acc[j][r], 0.f);

    __syncthreads();
#pragma unroll
    for (int j = 0; j < 8; ++j)
        *(float4*)&sA[row0 + j][c0] = make_float4(acc[j][0], acc[j][1], acc[j][2], acc[j][3]);
    __syncthreads();

    if (MODE == MODE_DEC) {
        if (tid < BM * 3) {
            int r = tid / 3, o = tid - 3 * (tid / 3);
            int gr = r0 + r;
            float sv = b2[o];
            for (int i = 0; i < H; ++i) sv = fmaf(sA[r][i], w2[(size_t)i * 3 + o], sv);
            if (gr < nrows) outp[(size_t)gr * 3 + o] = sv;
        }
        return;
    }

    {
        float4 bb = *(const float4*)&b2[c0];
#pragma unroll
        for (int j = 0; j < 8; ++j) { acc[j][0] = bb.x; acc[j][1] = bb.y; acc[j][2] = bb.z; acc[j][3] = bb.w; }
    }
    gemm_seg(sA, H, w2, row0, c0, acc);

    float4 g4 = *(const float4*)&g[c0];
    float4 be4 = *(const float4*)&be[c0];
#pragma unroll
    for (int j = 0; j < 8; ++j) {
        float s = acc[j][0] + acc[j][1] + acc[j][2] + acc[j][3];
        float q = acc[j][0] * acc[j][0] + acc[j][1] * acc[j][1] +
                  acc[j][2] * acc[j][2] + acc[j][3] * acc[j][3];
#pragma unroll
        for (int m = 1; m < 32; m <<= 1) { s += __shfl_xor(s, m); q += __shfl_xor(q, m); }
        float mean = s * (1.0f / 128.0f);
        float inv = rsqrtf(q * (1.0f / 128.0f) - mean * mean + 1e-5f);
        int gr = r0 + row0 + j;
        if (gr >= nrows) continue;
        float v0 = (acc[j][0] - mean) * inv * g4.x + be4.x;
        float v1 = (acc[j][1] - mean) * inv * g4.y + be4.y;
        float v2 = (acc[j][2] - mean) * inv * g4.z + be4.z;
        float v3 = (acc[j][3] - mean) * inv * g4.w + be4.w;
        *(float4*)&outp[(size_t)gr * H + c0] = make_float4(v0, v1, v2, v3);
        s4 pk = {f2bf(v0), f2bf(v1), f2bf(v2), f2bf(v3)};
        *(s4*)&hbfout[(size_t)gr * H + c0] = pk;
    }
}

// ================= launcher =================
static inline size_t align16(size_t x) { return (x + 15) & ~(size_t)15; }

extern "C" void kernel_launch(void* const* d_in, const int* in_sizes, int n_in,
                              void* d_out, int out_size, void* d_ws, size_t ws_size,
                              hipStream_t stream) {
    const float* x       = (const float*)d_in[0];
    const int*   ei      = (const int*)d_in[1];
    const float* eattr   = (const float*)d_in[2];
    const float* enc_w1  = (const float*)d_in[3];
    const float* enc_b1  = (const float*)d_in[4];
    const float* enc_w2  = (const float*)d_in[5];
    const float* enc_b2  = (const float*)d_in[6];
    const float* enc_g   = (const float*)d_in[7];
    const float* enc_be  = (const float*)d_in[8];
    const float* edge_w1 = (const float*)d_in[9];
    const float* edge_b1 = (const float*)d_in[10];
    const float* edge_w2 = (const float*)d_in[11];
    const float* edge_b2 = (const float*)d_in[12];
    const float* edge_g  = (const float*)d_in[13];
    const float* edge_be = (const float*)d_in[14];
    const float* node_w1 = (const float*)d_in[15];
    const float* node_b1 = (const float*)d_in[16];
    const float* node_w2 = (const float*)d_in[17];
    const float* node_b2 = (const float*)d_in[18];
    const float* node_g  = (const float*)d_in[19];
    const float* node_be = (const float*)d_in[20];
    const float* dec_w1  = (const float*)d_in[21];
    const float* dec_b1  = (const float*)d_in[22];
    const float* dec_w2  = (const float*)d_in[23];
    const float* dec_b2  = (const float*)d_in[24];

    const int N = in_sizes[0] / 10;
    const int E = in_sizes[1] / 2;
    const int* srcI = ei;
    const int* tgtI = ei + E;

    // ---- workspace layout (~106 MB) ----
    char* base = (char*)d_ws;
    size_t off = 0;
    float* h     = (float*)(base + off); off = align16(off + (size_t)N * H * 4);
    float* aggr  = (float*)(base + off); off = align16(off + (size_t)N * H * 4);
    short* hbf   = (short*)(base + off); off = align16(off + (size_t)N * H * 2);
    short* Tarr  = (short*)(base + off); off = align16(off + (size_t)N * H * 2);
    short* Sarr  = (short*)(base + off); off = align16(off + (size_t)N * H * 2);
    short* attrb = (short*)(base + off); off = align16(off + (size_t)E * 4 * 2);
    short* ewtsp = (short*)(base + off); off = align16(off + (size_t)4 * 16 * 4 * 512 * 2);
    short* ew2p  = (short*)(base + off); off = align16(off + (size_t)4 * 8 * 4 * 512 * 2);
    short* nw1p  = (short*)(base + off); off = align16(off + (size_t)4 * 8 * 8 * 512 * 2);
    short* nw2p  = (short*)(base + off); off = align16(off + (size_t)4 * 8 * 4 * 512 * 2);
    int*   cnt   = (int*)(base + off);  off = align16(off + (size_t)N * 4);
    int*   startp= (int*)(base + off);  off = align16(off + (size_t)(N + 1) * 4);
    int2*  stpair= (int2*)(base + off); off = align16(off + (size_t)E * 8);

    // ---- one-time packs ----
    pack_wts<<<dim3(64, 1, 4), 256, 0, stream>>>(edge_w1, ewtsp);
    pack_w<<<dim3(32, 1, 4), 256, 0, stream>>>(edge_w2, ew2p, H, 4);
    pack_w<<<dim3(64, 1, 4), 256, 0, stream>>>(node_w1, nw1p, 2 * H, 8);
    pack_w<<<dim3(32, 1, 4), 256, 0, stream>>>(node_w2, nw2p, H, 4);

    // ---- CSR build + tgt-sorted edge arrays ----
    hipMemsetAsync(cnt, 0, (size_t)N * 4, stream);
    csr_count<<<(E + 255) / 256, 256, 0, stream>>>(tgtI, cnt, E);
    scan_excl<<<1, SCAN_T, 0, stream>>>(cnt, startp, N);
    csr_scatter_reorder<<<(E + 255) / 256, 256, 0, stream>>>(
        tgtI, srcI, eattr, startp, stpair, attrb, E);

    const int gN64 = (N + BM - 1) / BM;
    mlp_small<MODE_ENC><<<gN64, 256, 0, stream>>>(
        x, enc_w1, enc_b1, enc_w2, enc_b2, enc_g, enc_be, h, hbf, N);

    const int gTS = (N + 127) / 128;
    const int gEe = (E + 127) / 128;
    const int gNN = (N + 255) / 256;

    // ts for layer 0 (also zeroes aggr)
    ts_mfma<<<gTS, 512, 0, stream>>>(
        hbf, ewtsp, edge_b1, Tarr, Sarr, aggr, N);

    for (int l = 0; l < 4; ++l) {
        const float* w1aG = edge_w1 + (size_t)l * 259 * 128 + 256 * 128;
        edge_fused<<<gEe, 512, 0, stream>>>(
            Tarr, Sarr, attrb, stpair, ew2p + (size_t)l * 8 * 4 * 512, w1aG,
            edge_b2 + (size_t)l * H, edge_g + (size_t)l * H, edge_be + (size_t)l * H,
            aggr, E);
        if (l < 3) {
            node_mfma<1><<<gNN, 1024, 0, stream>>>(
                hbf, aggr,
                nw1p + (size_t)l * 8 * 8 * 512, nw2p + (size_t)l * 8 * 4 * 512,
                node_b1 + (size_t)l * H, node_b2 + (size_t)l * H,
                node_g + (size_t)l * H, node_be + (size_t)l * H,
                h, hbf,
                ewtsp + (size_t)(l + 1) * 16 * 4 * 512, edge_b1 + (size_t)(l + 1) * H,
                Tarr, Sarr, aggr, N);
        } else {
            node_mfma<0><<<gNN, 1024, 0, stream>>>(
                hbf, aggr,
                nw1p + (size_t)l * 8 * 8 * 512, nw2p + (size_t)l * 8 * 4 * 512,
                node_b1 + (size_t)l * H, node_b2 + (size_t)l * H,
                node_g + (size_t)l * H, node_be + (size_t)l * H,
                h, hbf,
                nullptr, nullptr, nullptr, nullptr, nullptr, N);
        }
    }

    mlp_small<MODE_DEC><<<gN64, 256, 0, stream>>>(
        h, dec_w1, dec_b1, dec_w2, dec_b2, nullptr, nullptr, (float*)d_out, nullptr, N);
}

// Round 13
// 789.383 us; speedup vs baseline: 1.1347x; 1.0029x over previous
//
#include <hip/hip_runtime.h>

#define H 128
#define LPAD 132
#define BM 64

typedef __attribute__((ext_vector_type(8))) short bf8;
typedef __attribute__((ext_vector_type(4))) float f4;
typedef __attribute__((ext_vector_type(4))) short s4;

__device__ __forceinline__ short f2bf(float f) {
    unsigned u = __float_as_uint(f);
    unsigned r = u + 0x7FFFu + ((u >> 16) & 1u);   // round-to-nearest-even
    return (short)(r >> 16);
}
__device__ __forceinline__ float bf2f(unsigned lo16) {
    return __uint_as_float((lo16 & 0xFFFFu) << 16);
}

// ================= weight packing =================
// packed[m][kc][lane][i] = bf16( W[kc*32 + (lane>>4)*8 + i][m*16 + (lane&15)] ), 0 if k>=K
__global__ void pack_w(const float* __restrict__ W, short* __restrict__ out, int K, int KC) {
    const int layer = blockIdx.z;
    const float* Wl = W + (size_t)layer * K * H;
    short* ol = out + (size_t)layer * 8 * KC * 512;
    const int total = 8 * KC * 512;
    for (int idx = blockIdx.x * blockDim.x + threadIdx.x; idx < total; idx += gridDim.x * blockDim.x) {
        int i = idx & 7;
        int lane = (idx >> 3) & 63;
        int v = idx >> 9;
        int kc = v % KC;
        int m = v / KC;
        int k = kc * 32 + (lane >> 4) * 8 + i;
        int c = m * 16 + (lane & 15);
        float val = (k < K) ? Wl[(size_t)k * H + c] : 0.f;
        ol[idx] = f2bf(val);
    }
}

// TS weights: c'<128 -> edge_w1[l][k][c'] (tgt), c'>=128 -> edge_w1[l][128+k][c'-128] (src)
__global__ void pack_wts(const float* __restrict__ W /*[L][259][128]*/, short* __restrict__ out) {
    const int layer = blockIdx.z;
    const float* Wl = W + (size_t)layer * 259 * 128;
    short* ol = out + (size_t)layer * 16 * 4 * 512;
    const int total = 16 * 4 * 512;
    for (int idx = blockIdx.x * blockDim.x + threadIdx.x; idx < total; idx += gridDim.x * blockDim.x) {
        int i = idx & 7;
        int lane = (idx >> 3) & 63;
        int v = idx >> 9;
        int kc = v & 3;
        int m = v >> 2;
        int k = kc * 32 + (lane >> 4) * 8 + i;
        int c = m * 16 + (lane & 15);     // 0..255
        float val = (c < 128) ? Wl[(size_t)k * 128 + c] : Wl[(size_t)(128 + k) * 128 + (c - 128)];
        ol[idx] = f2bf(val);
    }
}

// ================= CSR build =================
__global__ void csr_count(const int* __restrict__ tgt, int* __restrict__ cnt, int E) {
    int e = blockIdx.x * blockDim.x + threadIdx.x;
    if (e < E) atomicAdd(&cnt[tgt[e]], 1);
}

#define SCAN_T 1024
__global__ __launch_bounds__(SCAN_T) void scan_excl(const int* __restrict__ cnt,
                                                    int* __restrict__ start, int n) {
    __shared__ int part[SCAN_T];
    int t = threadIdx.x;
    int chunk = (n + SCAN_T - 1) / SCAN_T;
    int lo = t * chunk, hi = min(lo + chunk, n);
    int s = 0;
    for (int i = lo; i < hi; ++i) s += cnt[i];
    part[t] = s;
    __syncthreads();
    for (int off = 1; off < SCAN_T; off <<= 1) {
        int v = (t >= off) ? part[t - off] : 0;
        __syncthreads();
        part[t] += v;
        __syncthreads();
    }
    int base = (t > 0) ? part[t - 1] : 0;
    for (int i = lo; i < hi; ++i) { start[i] = base; base += cnt[i]; }
}

// scatter + reorder fused: sorted position p gets edge e's (src,tgt) pair + attr ([E][4] bf16)
__global__ void csr_scatter_reorder(const int* __restrict__ tgtI, const int* __restrict__ srcI,
                                    const float* __restrict__ eattr,
                                    int* __restrict__ start,
                                    int2* __restrict__ stpair,
                                    short* __restrict__ attrb, int E) {
    int e = blockIdx.x * blockDim.x + threadIdx.x;
    if (e >= E) return;
    int t = tgtI[e];
    int p = atomicAdd(&start[t], 1);
    stpair[p] = make_int2(srcI[e], t);
    s4 vv = {};
    vv[0] = f2bf(eattr[(size_t)e * 3 + 0]);
    vv[1] = f2bf(eattr[(size_t)e * 3 + 1]);
    vv[2] = f2bf(eattr[(size_t)e * 3 + 2]);
    *(s4*)(attrb + (size_t)p * 4) = vv;
}

// ========== TS precompute (layer 0 only): Tarr/Sarr bf16 + fused aggr zeroing ==========
__global__ __launch_bounds__(512, 4) void ts_mfma(
    const short* __restrict__ hbf, const short* __restrict__ wtsp,
    const float* __restrict__ b1,
    short* __restrict__ Tarr, short* __restrict__ Sarr,
    float* __restrict__ aggr, int N) {
    __shared__ __align__(16) short sW[16 * 4 * 512];   // 64 KB
    const int tid = threadIdx.x;
    for (int t = tid; t < 16 * 4 * 512 / 8; t += 512) ((uint4*)sW)[t] = ((const uint4*)wtsp)[t];
    __syncthreads();

    const int lane = tid & 63;
    const int wv = tid >> 6;          // 0..7
    const int g = lane >> 4;
    const int er = lane & 15;
    const int n = blockIdx.x * 128 + wv * 16 + er;
    const int nC = (n < N) ? n : 0;
    const bf8* rT = (const bf8*)(hbf + (size_t)nC * H);

    f4 acc[16] = {};
#pragma unroll
    for (int kc = 0; kc < 4; ++kc) {
        bf8 b = rT[kc * 4 + g];
#pragma unroll
        for (int m = 0; m < 16; ++m)
            acc[m] = __builtin_amdgcn_mfma_f32_16x16x32_bf16(
                *(const bf8*)(sW + ((m * 4 + kc) * 64 + lane) * 8), b, acc[m], 0, 0, 0);
    }
    if (n >= N) return;
    short* oT = Tarr + (size_t)n * 128;
    short* oS = Sarr + (size_t)n * 128;
    float* oZ = aggr + (size_t)n * 128;
    const f4 zz = {0.f, 0.f, 0.f, 0.f};
#pragma unroll
    for (int m = 0; m < 16; ++m) {
        f4 v = acc[m];
        if (m < 8) {
            f4 bb = *(const f4*)(b1 + m * 16 + 4 * g);
            v = v + bb;
            *(f4*)(oZ + m * 16 + 4 * g) = zz;   // fused aggr zeroing
        }
        unsigned p0, p1;
        asm("v_cvt_pk_bf16_f32 %0, %1, %2" : "=v"(p0) : "v"(v[0]), "v"(v[1]));
        asm("v_cvt_pk_bf16_f32 %0, %1, %2" : "=v"(p1) : "v"(v[2]), "v"(v[3]));
        uint2 uu; uu.x = p0; uu.y = p1;
        if (m < 8) *(uint2*)(oT + m * 16 + 4 * g) = uu;
        else       *(uint2*)(oS + (m - 8) * 16 + 4 * g) = uu;
    }
}

// ================= fused edge kernel (128 edges / 512 threads) =================
// hid = relu(T[tgt]+S[src]+attr*W1a); msg = LN(hid@W2+b2);
// wave-private 8-row msg buffer, TWO passes (no block barrier), carry (cur,a0,a1)
// across passes -> atomic count identical to single-pass. LDS 50 KB -> 3 blocks/CU.
__global__ __launch_bounds__(512, 4) void edge_fused(
    const short* __restrict__ Tarr, const short* __restrict__ Sarr,
    const short* __restrict__ attrbf,
    const int2* __restrict__ stpair,
    const short* __restrict__ w2p,
    const float* __restrict__ w1aG,   // [3][128] f32 (attr rows of edge_w1)
    const float* __restrict__ b2,
    const float* __restrict__ gamma, const float* __restrict__ beta,
    float* __restrict__ aggr, int nrows) {
    __shared__ __align__(16) short sW2[8 * 4 * 512];     // 32 KB
    __shared__ float sw1a[3 * 128];                      // 1.5 KB
    __shared__ __align__(16) unsigned smsg[8 * 8 * 64];  // 16 KB: [wave][8 rows][64 dwords]
    __shared__ int stgt[128];

    const int tid = threadIdx.x;
    for (int t = tid; t < 8 * 4 * 512 / 8; t += 512) ((uint4*)sW2)[t] = ((const uint4*)w2p)[t];
    if (tid < 384) sw1a[tid] = w1aG[tid];
    const int e0b = blockIdx.x * 128;
    if (tid < 128) {
        int ee = e0b + tid;
        stgt[tid] = (ee < nrows) ? stpair[ee].y : -1;
    }
    __syncthreads();

    const int lane = tid & 63;
    const int wv = tid >> 6;          // 0..7
    const int g = lane >> 4;
    const int er = lane & 15;
    const int le = wv * 16 + er;      // local edge 0..127
    const int e = e0b + le;
    const bool valid = e < nrows;
    const int eC = valid ? e : 0;
    const int2 st = stpair[eC];
    const int tS = st.x;
    const int tT = st.y;

    uint2 au = *(const uint2*)(attrbf + (size_t)eC * 4);
    const float at0 = bf2f(au.x), at1 = bf2f(au.x >> 16), at2 = bf2f(au.y);

    const short* Tp = Tarr + (size_t)tT * 128;
    const short* Sp = Sarr + (size_t)tS * 128;

    // ---------- hid build + GEMM2 ----------
    f4 acc2[8] = {};
#pragma unroll
    for (int kc2 = 0; kc2 < 4; ++kc2) {
        const int c0 = kc2 * 32 + 8 * g;
        uint4 tu = *(const uint4*)(Tp + c0);
        uint4 su = *(const uint4*)(Sp + c0);
        unsigned tw[4] = {tu.x, tu.y, tu.z, tu.w};
        unsigned swd[4] = {su.x, su.y, su.z, su.w};
        float hv[8];
#pragma unroll
        for (int p = 0; p < 4; ++p) {
            int j0 = 2 * p;
            float t0 = bf2f(tw[p]), t1 = bf2f(tw[p] >> 16);
            float s0 = bf2f(swd[p]), s1 = bf2f(swd[p] >> 16);
            float a = t0 + s0 + at0 * sw1a[c0 + j0] + at1 * sw1a[128 + c0 + j0] + at2 * sw1a[256 + c0 + j0];
            hv[j0] = fmaxf(a, 0.f);
            float b = t1 + s1 + at0 * sw1a[c0 + j0 + 1] + at1 * sw1a[128 + c0 + j0 + 1] + at2 * sw1a[256 + c0 + j0 + 1];
            hv[j0 + 1] = fmaxf(b, 0.f);
        }
        bf8 bfr;
        unsigned* bu = (unsigned*)&bfr;
#pragma unroll
        for (int p = 0; p < 4; ++p)
            asm("v_cvt_pk_bf16_f32 %0, %1, %2" : "=v"(bu[p]) : "v"(hv[2 * p]), "v"(hv[2 * p + 1]));
#pragma unroll
        for (int m = 0; m < 8; ++m)
            acc2[m] = __builtin_amdgcn_mfma_f32_16x16x32_bf16(
                *(const bf8*)(sW2 + ((m * 4 + kc2) * 64 + lane) * 8), bfr, acc2[m], 0, 0, 0);
    }

    // ---------- bias2 + LayerNorm ----------
    float o[8][4];
    float s = 0.f, q = 0.f;
#pragma unroll
    for (int m = 0; m < 8; ++m) {
        f4 bb = *(const f4*)(b2 + m * 16 + 4 * g);
#pragma unroll
        for (int r = 0; r < 4; ++r) {
            float v = acc2[m][r] + bb[r];
            o[m][r] = v; s += v; q += v * v;
        }
    }
    s += __shfl_xor(s, 16, 64); q += __shfl_xor(q, 16, 64);
    s += __shfl_xor(s, 32, 64); q += __shfl_xor(q, 32, 64);
    const float mean = s * (1.f / 128.f);
    const float inv = rsqrtf(q * (1.f / 128.f) - mean * mean + 1e-5f);

    // ---------- pack normalized msg into registers (zeros for invalid edges) ----------
    unsigned pm[8][2];
#pragma unroll
    for (int m = 0; m < 8; ++m) {
        f4 gg = *(const f4*)(gamma + m * 16 + 4 * g);
        f4 be4 = *(const f4*)(beta + m * 16 + 4 * g);
        float v0 = valid ? ((o[m][0] - mean) * inv * gg[0] + be4[0]) : 0.f;
        float v1 = valid ? ((o[m][1] - mean) * inv * gg[1] + be4[1]) : 0.f;
        float v2 = valid ? ((o[m][2] - mean) * inv * gg[2] + be4[2]) : 0.f;
        float v3 = valid ? ((o[m][3] - mean) * inv * gg[3] + be4[3]) : 0.f;
        asm("v_cvt_pk_bf16_f32 %0, %1, %2" : "=v"(pm[m][0]) : "v"(v0), "v"(v1));
        asm("v_cvt_pk_bf16_f32 %0, %1, %2" : "=v"(pm[m][1]) : "v"(v2), "v"(v3));
    }

    // ---------- wave-private two-pass stage + segmented reduction ----------
    unsigned* wbuf = smsg + wv * (8 * 64);   // this wave's 8-row buffer
    const int rloc = er & 7;                 // row within buffer
    const unsigned swz = (unsigned)(rloc << 3);
    const int c2 = lane;                     // channel pair 2*c2, 2*c2+1
    float a0 = 0.f, a1 = 0.f;
    int cur = stgt[wv * 16];
#pragma unroll
    for (int pass = 0; pass < 2; ++pass) {
        if ((er >> 3) == pass) {
            unsigned* row = wbuf + rloc * 64;
#pragma unroll
            for (int m = 0; m < 8; ++m) {
                unsigned d0 = ((unsigned)(m * 8 + 2 * g)) ^ swz;
                uint2 uu; uu.x = pm[m][0]; uu.y = pm[m][1];
                *(uint2*)(row + d0) = uu;
            }
        }
        // DS ops are in-order per wave; fence orders compiler + waits write-completion
        asm volatile("s_waitcnt lgkmcnt(0)" ::: "memory");
#pragma unroll
        for (int j = 0; j < 8; ++j) {
            int le2 = wv * 16 + pass * 8 + j;
            int tg = stgt[le2];
            if (tg != cur) {
                if (cur >= 0) {
                    atomicAdd(&aggr[(size_t)cur * 128 + 2 * c2], a0);
                    atomicAdd(&aggr[(size_t)cur * 128 + 2 * c2 + 1], a1);
                }
                a0 = 0.f; a1 = 0.f; cur = tg;
            }
            unsigned u = wbuf[j * 64 + (c2 ^ (j << 3))];
            a0 += __uint_as_float(u << 16);
            a1 += __uint_as_float(u & 0xFFFF0000u);
        }
        if (pass == 0) asm volatile("s_waitcnt lgkmcnt(0)" ::: "memory");  // reads done before overwrite
    }
    if (cur >= 0) {
        atomicAdd(&aggr[(size_t)cur * 128 + 2 * c2], a0);
        atomicAdd(&aggr[(size_t)cur * 128 + 2 * c2 + 1], a1);
    }
}

// ================= node MLP (LDS weights); NEXT=1 also computes Tarr/Sarr(l+1) + zeroes aggr =====
template <int NEXT>
__global__ __launch_bounds__(1024, 4) void node_mfma(
    const short* __restrict__ hbf, const float* __restrict__ aggrf,
    const short* __restrict__ w1p, const short* __restrict__ w2p,
    const float* __restrict__ b1, const float* __restrict__ b2,
    const float* __restrict__ gamma, const float* __restrict__ beta,
    float* __restrict__ outp, short* __restrict__ hbfout,
    const short* __restrict__ wtsnext, const float* __restrict__ b1next,
    short* __restrict__ TarrO, short* __restrict__ SarrO,
    float* __restrict__ aggrZ, int nrows) {
    __shared__ __align__(16) short sW1[8 * 8 * 512];   // 64 KB
    __shared__ __align__(16) short sW2[8 * 4 * 512];   // 32 KB

    const int tid = threadIdx.x;
    for (int t = tid; t < 8 * 8 * 512 / 8; t += 1024) ((uint4*)sW1)[t] = ((const uint4*)w1p)[t];
    for (int t = tid; t < 8 * 4 * 512 / 8; t += 1024) ((uint4*)sW2)[t] = ((const uint4*)w2p)[t];
    __syncthreads();

    const int lane = tid & 63;
    const int wv = tid >> 6;
    const int g = lane >> 4;
    const int er = lane & 15;
    const int e = blockIdx.x * 256 + wv * 16 + er;
    const bool valid = e < nrows;
    const int eC = valid ? e : 0;

    const bf8* rT = (const bf8*)(hbf + (size_t)eC * H);
    const f4* ra = (const f4*)(aggrf + (size_t)eC * H);

    f4 acc1[8] = {};
#pragma unroll
    for (int kc = 0; kc < 4; ++kc) {
        bf8 b = rT[kc * 4 + g];
#pragma unroll
        for (int m = 0; m < 8; ++m)
            acc1[m] = __builtin_amdgcn_mfma_f32_16x16x32_bf16(
                *(const bf8*)(sW1 + ((m * 8 + kc) * 64 + lane) * 8), b, acc1[m], 0, 0, 0);
    }
#pragma unroll
    for (int kc = 4; kc < 8; ++kc) {
        f4 a0 = ra[(kc - 4) * 8 + g * 2];
        f4 a1 = ra[(kc - 4) * 8 + g * 2 + 1];
        bf8 b;
        unsigned* bu = (unsigned*)&b;
        asm("v_cvt_pk_bf16_f32 %0, %1, %2" : "=v"(bu[0]) : "v"(a0[0]), "v"(a0[1]));
        asm("v_cvt_pk_bf16_f32 %0, %1, %2" : "=v"(bu[1]) : "v"(a0[2]), "v"(a0[3]));
        asm("v_cvt_pk_bf16_f32 %0, %1, %2" : "=v"(bu[2]) : "v"(a1[0]), "v"(a1[1]));
        asm("v_cvt_pk_bf16_f32 %0, %1, %2" : "=v"(bu[3]) : "v"(a1[2]), "v"(a1[3]));
#pragma unroll
        for (int m = 0; m < 8; ++m)
            acc1[m] = __builtin_amdgcn_mfma_f32_16x16x32_bf16(
                *(const bf8*)(sW1 + ((m * 8 + kc) * 64 + lane) * 8), b, acc1[m], 0, 0, 0);
    }

    float h1[8][4];
#pragma unroll
    for (int m = 0; m < 8; ++m) {
        f4 bb = *(const f4*)(b1 + m * 16 + 4 * g);
#pragma unroll
        for (int r = 0; r < 4; ++r) h1[m][r] = fmaxf(acc1[m][r] + bb[r], 0.f);
    }

    unsigned pk[8][2];
#pragma unroll
    for (int m = 0; m < 8; ++m)
#pragma unroll
        for (int hh = 0; hh < 2; ++hh)
            asm("v_cvt_pk_bf16_f32 %0, %1, %2"
                : "=v"(pk[m][hh]) : "v"(h1[m][2 * hh]), "v"(h1[m][2 * hh + 1]));

    f4 acc2[8] = {};
#pragma unroll
    for (int kc2 = 0; kc2 < 4; ++kc2) {
        bf8 bfr;
        unsigned* bu = (unsigned*)&bfr;
#pragma unroll
        for (int p = 0; p < 4; ++p) {
            int sl = er + 16 * (2 * (g & 1) + (p >> 1));
            unsigned lo = (unsigned)__shfl((int)pk[2 * kc2 + 0][p & 1], sl, 64);
            unsigned hi = (unsigned)__shfl((int)pk[2 * kc2 + 1][p & 1], sl, 64);
            bu[p] = (g >> 1) ? hi : lo;
        }
#pragma unroll
        for (int m = 0; m < 8; ++m)
            acc2[m] = __builtin_amdgcn_mfma_f32_16x16x32_bf16(
                *(const bf8*)(sW2 + ((m * 4 + kc2) * 64 + lane) * 8), bfr, acc2[m], 0, 0, 0);
    }

    float o[8][4];
    float s = 0.f, q = 0.f;
#pragma unroll
    for (int m = 0; m < 8; ++m) {
        f4 bb = *(const f4*)(b2 + m * 16 + 4 * g);
#pragma unroll
        for (int r = 0; r < 4; ++r) {
            float v = acc2[m][r] + bb[r];
            o[m][r] = v; s += v; q += v * v;
        }
    }
    s += __shfl_xor(s, 16, 64); q += __shfl_xor(q, 16, 64);
    s += __shfl_xor(s, 32, 64); q += __shfl_xor(q, 32, 64);
    const float mean = s * (1.f / 128.f);
    const float inv = rsqrtf(q * (1.f / 128.f) - mean * mean + 1e-5f);

    // ---------- residual epilogue; keep packed new-h in registers for NEXT ----------
    float* hp = outp + (size_t)eC * H;
    short* hb = hbfout + (size_t)eC * H;
    unsigned pkh[8][2];
#pragma unroll
    for (int m = 0; m < 8; ++m) {
        f4 gg = *(const f4*)(gamma + m * 16 + 4 * g);
        f4 be4 = *(const f4*)(beta + m * 16 + 4 * g);
        f4 hv;
        if (valid) hv = *(const f4*)(hp + m * 16 + 4 * g);
        else hv = f4{0.f, 0.f, 0.f, 0.f};
        f4 nv;
#pragma unroll
        for (int r = 0; r < 4; ++r)
            nv[r] = hv[r] + (o[m][r] - mean) * inv * gg[r] + be4[r];
        asm("v_cvt_pk_bf16_f32 %0, %1, %2" : "=v"(pkh[m][0]) : "v"(nv[0]), "v"(nv[1]));
        asm("v_cvt_pk_bf16_f32 %0, %1, %2" : "=v"(pkh[m][1]) : "v"(nv[2]), "v"(nv[3]));
        if (valid) {
            *(f4*)(hp + m * 16 + 4 * g) = nv;
            if (NEXT) {
                uint2 uu; uu.x = pkh[m][0]; uu.y = pkh[m][1];
                *(uint2*)(hb + m * 16 + 4 * g) = uu;
            }
        }
    }

    if (NEXT) {
        // build TS B-frags from new h via the (verified) transpose shuffle
        bf8 bfrs[4];
#pragma unroll
        for (int kc = 0; kc < 4; ++kc) {
            unsigned* bu = (unsigned*)&bfrs[kc];
#pragma unroll
            for (int p = 0; p < 4; ++p) {
                int sl = er + 16 * (2 * (g & 1) + (p >> 1));
                unsigned lo = (unsigned)__shfl((int)pkh[2 * kc + 0][p & 1], sl, 64);
                unsigned hi = (unsigned)__shfl((int)pkh[2 * kc + 1][p & 1], sl, 64);
                bu[p] = (g >> 1) ? hi : lo;
            }
        }
        const bf8* wN = (const bf8*)wtsnext + lane;
        // T half (m = 0..7), bias b1next
        f4 accT[8] = {};
#pragma unroll
        for (int kc = 0; kc < 4; ++kc)
#pragma unroll
            for (int m = 0; m < 8; ++m)
                accT[m] = __builtin_amdgcn_mfma_f32_16x16x32_bf16(
                    wN[(m * 4 + kc) * 64], bfrs[kc], accT[m], 0, 0, 0);
        if (valid) {
            short* oT = TarrO + (size_t)eC * 128;
            float* oZ = aggrZ + (size_t)eC * 128;
            const f4 zz = {0.f, 0.f, 0.f, 0.f};
#pragma unroll
            for (int m = 0; m < 8; ++m) {
                f4 bb = *(const f4*)(b1next + m * 16 + 4 * g);
                f4 v = accT[m] + bb;
                unsigned p0, p1;
                asm("v_cvt_pk_bf16_f32 %0, %1, %2" : "=v"(p0) : "v"(v[0]), "v"(v[1]));
                asm("v_cvt_pk_bf16_f32 %0, %1, %2" : "=v"(p1) : "v"(v[2]), "v"(v[3]));
                uint2 uu; uu.x = p0; uu.y = p1;
                *(uint2*)(oT + m * 16 + 4 * g) = uu;
                *(f4*)(oZ + m * 16 + 4 * g) = zz;   // zero aggr for next layer
            }
        }
        // S half (m = 8..15), no bias
        f4 accS[8] = {};
#pragma unroll
        for (int kc = 0; kc < 4; ++kc)
#pragma unroll
            for (int m = 0; m < 8; ++m)
                accS[m] = __builtin_amdgcn_mfma_f32_16x16x32_bf16(
                    wN[((m + 8) * 4 + kc) * 64], bfrs[kc], accS[m], 0, 0, 0);
        if (valid) {
            short* oS = SarrO + (size_t)eC * 128;
#pragma unroll
            for (int m = 0; m < 8; ++m) {
                f4 v = accS[m];
                unsigned p0, p1;
                asm("v_cvt_pk_bf16_f32 %0, %1, %2" : "=v"(p0) : "v"(v[0]), "v"(v[1]));
                asm("v_cvt_pk_bf16_f32 %0, %1, %2" : "=v"(p1) : "v"(v[2]), "v"(v[3]));
                uint2 uu; uu.x = p0; uu.y = p1;
                *(uint2*)(oS + m * 16 + 4 * g) = uu;
            }
        }
    }
}

// ================= fp32 ENC / DEC (small) =================
enum { MODE_ENC = 0, MODE_DEC = 3 };

__device__ __forceinline__ void fma_row(float acc[4], float a, const float4& b) {
    acc[0] = fmaf(a, b.x, acc[0]);
    acc[1] = fmaf(a, b.y, acc[1]);
    acc[2] = fmaf(a, b.z, acc[2]);
    acc[3] = fmaf(a, b.w, acc[3]);
}

__device__ __forceinline__ void gemm_seg(const float (*A)[LPAD], int K,
                                         const float* __restrict__ B,
                                         int row0, int c0, float acc[8][4]) {
    int k = 0;
    for (; k + 4 <= K; k += 4) {
        float4 b0 = *(const float4*)(B + (size_t)(k + 0) * H + c0);
        float4 b1 = *(const float4*)(B + (size_t)(k + 1) * H + c0);
        float4 b2 = *(const float4*)(B + (size_t)(k + 2) * H + c0);
        float4 b3 = *(const float4*)(B + (size_t)(k + 3) * H + c0);
#pragma unroll
        for (int j = 0; j < 8; ++j) {
            float4 a = *(const float4*)(&A[row0 + j][k]);
            fma_row(acc[j], a.x, b0);
            fma_row(acc[j], a.y, b1);
            fma_row(acc[j], a.z, b2);
            fma_row(acc[j], a.w, b3);
        }
    }
    for (; k < K; ++k) {
        float4 bv = *(const float4*)(B + (size_t)k * H + c0);
#pragma unroll
        for (int j = 0; j < 8; ++j) fma_row(acc[j], A[row0 + j][k], bv);
    }
}

template <int MODE>
__global__ __launch_bounds__(256, 2) void mlp_small(
    const float* __restrict__ in0,
    const float* __restrict__ w1, const float* __restrict__ b1,
    const float* __restrict__ w2, const float* __restrict__ b2,
    const float* __restrict__ g, const float* __restrict__ be,
    float* __restrict__ outp, short* __restrict__ hbfout, int nrows) {
    __shared__ __align__(16) float sA[BM][LPAD];

    const int tid = threadIdx.x;
    const int tr = tid >> 5, tc = tid & 31;
    const int c0 = tc * 4, row0 = tr * 8;
    const int r0 = blockIdx.x * BM;

    if (MODE == MODE_ENC) {
        for (int idx = tid; idx < BM * 10; idx += 256) {
            int r = idx / 10, c = idx - 10 * (idx / 10);
            int n = r0 + r;
            sA[r][c] = (n < nrows) ? in0[(size_t)n * 10 + c] : 0.f;
        }
    } else {
        for (int idx = tid; idx < BM * 32; idx += 256) {
            int r = idx >> 5, qq = idx & 31;
            int n = r0 + r;
            float4 v0 = make_float4(0.f, 0.f, 0.f, 0.f);
            if (n < nrows) v0 = ((const float4*)in0)[(size_t)n * 32 + qq];
            *(float4*)&sA[r][qq * 4] = v0;
        }
    }
    __syncthreads();

    float acc[8][4];
    {
        float4 bb = *(const float4*)&b1[c0];
#pragma unroll
        for (int j = 0; j < 8; ++j) { acc[j][0] = bb.x; acc[j][1] = bb.y; acc[j][2] = bb.z; acc[j][3] = bb.w; }
    }
    gemm_seg(sA, (MODE == MODE_ENC) ? 10 : H, w1, row0, c0, acc);
#pragma unroll
    for (int j = 0; j < 8; ++j)
#pragma unroll
        for (int r = 0; r < 4; ++r) acc[j][r] = fmaxf(acc[j][r], 0.f);

    __syncthreads();
#pragma unroll
    for (int j = 0; j < 8; ++j)
        *(float4*)&sA[row0 + j][c0] = make_float4(acc[j][0], acc[j][1], acc[j][2], acc[j][3]);
    __syncthreads();

    if (MODE == MODE_DEC) {
        if (tid < BM * 3) {
            int r = tid / 3, o = tid - 3 * (tid / 3);
            int gr = r0 + r;
            float sv = b2[o];
            for (int i = 0; i < H; ++i) sv = fmaf(sA[r][i], w2[(size_t)i * 3 + o], sv);
            if (gr < nrows) outp[(size_t)gr * 3 + o] = sv;
        }
        return;
    }

    {
        float4 bb = *(const float4*)&b2[c0];
#pragma unroll
        for (int j = 0; j < 8; ++j) { acc[j][0] = bb.x; acc[j][1] = bb.y; acc[j][2] = bb.z; acc[j][3] = bb.w; }
    }
    gemm_seg(sA, H, w2, row0, c0, acc);

    float4 g4 = *(const float4*)&g[c0];
    float4 be4 = *(const float4*)&be[c0];
#pragma unroll
    for (int j = 0; j < 8; ++j) {
        float s = acc[j][0] + acc[j][1] + acc[j][2] + acc[j][3];
        float q = acc[j][0] * acc[j][0] + acc[j][1] * acc[j][1] +
                  acc[j][2] * acc[j][2] + acc[j][3] * acc[j][3];
#pragma unroll
        for (int m = 1; m < 32; m <<= 1) { s += __shfl_xor(s, m); q += __shfl_xor(q, m); }
        float mean = s * (1.0f / 128.0f);
        float inv = rsqrtf(q * (1.0f / 128.0f) - mean * mean + 1e-5f);
        int gr = r0 + row0 + j;
        if (gr >= nrows) continue;
        float v0 = (acc[j][0] - mean) * inv * g4.x + be4.x;
        float v1 = (acc[j][1] - mean) * inv * g4.y + be4.y;
        float v2 = (acc[j][2] - mean) * inv * g4.z + be4.z;
        float v3 = (acc[j][3] - mean) * inv * g4.w + be4.w;
        *(float4*)&outp[(size_t)gr * H + c0] = make_float4(v0, v1, v2, v3);
        s4 pk = {f2bf(v0), f2bf(v1), f2bf(v2), f2bf(v3)};
        *(s4*)&hbfout[(size_t)gr * H + c0] = pk;
    }
}

// ================= launcher =================
static inline size_t align16(size_t x) { return (x + 15) & ~(size_t)15; }

extern "C" void kernel_launch(void* const* d_in, const int* in_sizes, int n_in,
                              void* d_out, int out_size, void* d_ws, size_t ws_size,
                              hipStream_t stream) {
    const float* x       = (const float*)d_in[0];
    const int*   ei      = (const int*)d_in[1];
    const float* eattr   = (const float*)d_in[2];
    const float* enc_w1  = (const float*)d_in[3];
    const float* enc_b1  = (const float*)d_in[4];
    const float* enc_w2  = (const float*)d_in[5];
    const float* enc_b2  = (const float*)d_in[6];
    const float* enc_g   = (const float*)d_in[7];
    const float* enc_be  = (const float*)d_in[8];
    const float* edge_w1 = (const float*)d_in[9];
    const float* edge_b1 = (const float*)d_in[10];
    const float* edge_w2 = (const float*)d_in[11];
    const float* edge_b2 = (const float*)d_in[12];
    const float* edge_g  = (const float*)d_in[13];
    const float* edge_be = (const float*)d_in[14];
    const float* node_w1 = (const float*)d_in[15];
    const float* node_b1 = (const float*)d_in[16];
    const float* node_w2 = (const float*)d_in[17];
    const float* node_b2 = (const float*)d_in[18];
    const float* node_g  = (const float*)d_in[19];
    const float* node_be = (const float*)d_in[20];
    const float* dec_w1  = (const float*)d_in[21];
    const float* dec_b1  = (const float*)d_in[22];
    const float* dec_w2  = (const float*)d_in[23];
    const float* dec_b2  = (const float*)d_in[24];

    const int N = in_sizes[0] / 10;
    const int E = in_sizes[1] / 2;
    const int* srcI = ei;
    const int* tgtI = ei + E;

    // ---- workspace layout (~106 MB) ----
    char* base = (char*)d_ws;
    size_t off = 0;
    float* h     = (float*)(base + off); off = align16(off + (size_t)N * H * 4);
    float* aggr  = (float*)(base + off); off = align16(off + (size_t)N * H * 4);
    short* hbf   = (short*)(base + off); off = align16(off + (size_t)N * H * 2);
    short* Tarr  = (short*)(base + off); off = align16(off + (size_t)N * H * 2);
    short* Sarr  = (short*)(base + off); off = align16(off + (size_t)N * H * 2);
    short* attrb = (short*)(base + off); off = align16(off + (size_t)E * 4 * 2);
    short* ewtsp = (short*)(base + off); off = align16(off + (size_t)4 * 16 * 4 * 512 * 2);
    short* ew2p  = (short*)(base + off); off = align16(off + (size_t)4 * 8 * 4 * 512 * 2);
    short* nw1p  = (short*)(base + off); off = align16(off + (size_t)4 * 8 * 8 * 512 * 2);
    short* nw2p  = (short*)(base + off); off = align16(off + (size_t)4 * 8 * 4 * 512 * 2);
    int*   cnt   = (int*)(base + off);  off = align16(off + (size_t)N * 4);
    int*   startp= (int*)(base + off);  off = align16(off + (size_t)(N + 1) * 4);
    int2*  stpair= (int2*)(base + off); off = align16(off + (size_t)E * 8);

    // ---- one-time packs ----
    pack_wts<<<dim3(64, 1, 4), 256, 0, stream>>>(edge_w1, ewtsp);
    pack_w<<<dim3(32, 1, 4), 256, 0, stream>>>(edge_w2, ew2p, H, 4);
    pack_w<<<dim3(64, 1, 4), 256, 0, stream>>>(node_w1, nw1p, 2 * H, 8);
    pack_w<<<dim3(32, 1, 4), 256, 0, stream>>>(node_w2, nw2p, H, 4);

    // ---- CSR build + tgt-sorted edge arrays ----
    hipMemsetAsync(cnt, 0, (size_t)N * 4, stream);
    csr_count<<<(E + 255) / 256, 256, 0, stream>>>(tgtI, cnt, E);
    scan_excl<<<1, SCAN_T, 0, stream>>>(cnt, startp, N);
    csr_scatter_reorder<<<(E + 255) / 256, 256, 0, stream>>>(
        tgtI, srcI, eattr, startp, stpair, attrb, E);

    const int gN64 = (N + BM - 1) / BM;
    mlp_small<MODE_ENC><<<gN64, 256, 0, stream>>>(
        x, enc_w1, enc_b1, enc_w2, enc_b2, enc_g, enc_be, h, hbf, N);

    const int gTS = (N + 127) / 128;
    const int gEe = (E + 127) / 128;
    const int gNN = (N + 255) / 256;

    // ts for layer 0 (also zeroes aggr)
    ts_mfma<<<gTS, 512, 0, stream>>>(
        hbf, ewtsp, edge_b1, Tarr, Sarr, aggr, N);

    for (int l = 0; l < 4; ++l) {
        const float* w1aG = edge_w1 + (size_t)l * 259 * 128 + 256 * 128;
        edge_fused<<<gEe, 512, 0, stream>>>(
            Tarr, Sarr, attrb, stpair, ew2p + (size_t)l * 8 * 4 * 512, w1aG,
            edge_b2 + (size_t)l * H, edge_g + (size_t)l * H, edge_be + (size_t)l * H,
            aggr, E);
        if (l < 3) {
            node_mfma<1><<<gNN, 1024, 0, stream>>>(
                hbf, aggr,
                nw1p + (size_t)l * 8 * 8 * 512, nw2p + (size_t)l * 8 * 4 * 512,
                node_b1 + (size_t)l * H, node_b2 + (size_t)l * H,
                node_g + (size_t)l * H, node_be + (size_t)l * H,
                h, hbf,
                ewtsp + (size_t)(l + 1) * 16 * 4 * 512, edge_b1 + (size_t)(l + 1) * H,
                Tarr, Sarr, aggr, N);
        } else {
            node_mfma<0><<<gNN, 1024, 0, stream>>>(
                hbf, aggr,
                nw1p + (size_t)l * 8 * 8 * 512, nw2p + (size_t)l * 8 * 4 * 512,
                node_b1 + (size_t)l * H, node_b2 + (size_t)l * H,
                node_g + (size_t)l * H, node_be + (size_t)l * H,
                h, hbf,
                nullptr, nullptr, nullptr, nullptr, nullptr, N);
        }
    }

    mlp_small<MODE_DEC><<<gN64, 256, 0, stream>>>(
        h, dec_w1, dec_b1, dec_w2, dec_b2, nullptr, nullptr, (float*)d_out, nullptr, N);
}